// Round 1
// baseline (3786.128 us; speedup 1.0000x reference)
//
#include <hip/hip_runtime.h>

#define HD 128

constexpr int T_NC = 100000;
constexpr int T_ND = 20000;
constexpr int T_NG = 50000;
constexpr int T_E  = 150000;
constexpr int T_EP = 100000;

__device__ __forceinline__ float gelu_f(float x) {
    return 0.5f * x * (1.0f + erff(x * 0.70710678118654752f));
}

// Generic fused GEMM over rows: acc[r][c] = sum_p A_p[r][:] @ W_p[:][c]
// (A_p rows optionally scaled by 1/max(cnt_p[r],1) -- mean aggregation)
// Epilogue:
//   LNG=true : v = (acc + bias0[c] + bias1[c]) * scale + (res ? res[r][c] : 0)
//              then row-LayerNorm(v)*g+b, exact GELU, write out.
//   LNG=false: out[r][c] = acc (plain).
// Tile: 128 rows x 128 cols, 256 threads, each thread 8 rows x 8 cols.
template<int NP, bool LNG>
__global__ __launch_bounds__(256, 1)
void gemm_fused(const float* __restrict__ A0, const float* __restrict__ W0, const int* __restrict__ c0p,
                const float* __restrict__ A1, const float* __restrict__ W1, const int* __restrict__ c1p,
                const float* __restrict__ A2, const float* __restrict__ W2, const int* __restrict__ c2p,
                const float* __restrict__ A3, const float* __restrict__ W3, const int* __restrict__ c3p,
                const float* __restrict__ bias0, const float* __restrict__ bias1,
                float scale, const float* __restrict__ res,
                const float* __restrict__ g_ln, const float* __restrict__ b_ln,
                float* __restrict__ out, int M)
{
    __shared__ float As[HD * 133];   // A tile, stride 133 floats (conflict-free reads)
    __shared__ float Wt[HD * HD];    // W tile, row-major

    const int tid = threadIdx.x;
    const int cg = tid & 15;         // col group: cols cg*8 .. cg*8+7
    const int rg = tid >> 4;         // row group: rows rg*8 .. rg*8+7
    const int row0 = blockIdx.x * 128;

    float acc[8][8];
    #pragma unroll
    for (int q = 0; q < 8; ++q)
        #pragma unroll
        for (int c = 0; c < 8; ++c) acc[q][c] = 0.f;

    #pragma unroll
    for (int p = 0; p < NP; ++p) {
        const float* A = (p == 0) ? A0 : (p == 1) ? A1 : (p == 2) ? A2 : A3;
        const float* W = (p == 0) ? W0 : (p == 1) ? W1 : (p == 2) ? W2 : W3;
        const int*  cp = (p == 0) ? c0p : (p == 1) ? c1p : (p == 2) ? c2p : c3p;

        __syncthreads();  // LDS reuse across pairs
        // stage W (128x128)
        for (int idx = tid; idx < 128 * 32; idx += 256) {
            int k  = idx >> 5;
            int c4 = (idx & 31) << 2;
            *(float4*)(Wt + k * 128 + c4) = *(const float4*)(W + k * 128 + c4);
        }
        // stage A rows (scaled by 1/cnt for mean aggregation)
        for (int idx = tid; idx < 128 * 32; idx += 256) {
            int r  = idx >> 5;
            int c4 = (idx & 31) << 2;
            int gr = row0 + r;
            float4 v = make_float4(0.f, 0.f, 0.f, 0.f);
            float rs = 1.f;
            if (gr < M) {
                v = *(const float4*)(A + (size_t)gr * HD + c4);
                if (cp) { int cv = cp[gr]; rs = 1.f / (float)(cv > 1 ? cv : 1); }
            }
            float* dst = As + r * 133 + c4;
            dst[0] = v.x * rs; dst[1] = v.y * rs; dst[2] = v.z * rs; dst[3] = v.w * rs;
        }
        __syncthreads();

        const float* ap = As + (rg * 8) * 133;
        #pragma unroll 2
        for (int i = 0; i < 128; ++i) {
            float a[8];
            #pragma unroll
            for (int q = 0; q < 8; ++q) a[q] = ap[q * 133 + i];
            const float4 w0 = *(const float4*)(Wt + i * 128 + cg * 8);
            const float4 w1 = *(const float4*)(Wt + i * 128 + cg * 8 + 4);
            float w[8] = {w0.x, w0.y, w0.z, w0.w, w1.x, w1.y, w1.z, w1.w};
            #pragma unroll
            for (int q = 0; q < 8; ++q)
                #pragma unroll
                for (int c = 0; c < 8; ++c)
                    acc[q][c] = fmaf(a[q], w[c], acc[q][c]);
        }
    }

    // ---- epilogue ----
    if (!LNG) {
        #pragma unroll
        for (int q = 0; q < 8; ++q) {
            int gr = row0 + rg * 8 + q;
            if (gr < M) {
                float4 o0 = make_float4(acc[q][0], acc[q][1], acc[q][2], acc[q][3]);
                float4 o1 = make_float4(acc[q][4], acc[q][5], acc[q][6], acc[q][7]);
                *(float4*)(out + (size_t)gr * HD + cg * 8)     = o0;
                *(float4*)(out + (size_t)gr * HD + cg * 8 + 4) = o1;
            }
        }
        return;
    }

    float b01[8], gl[8], bb[8];
    #pragma unroll
    for (int c = 0; c < 8; ++c) {
        float b = 0.f;
        if (bias0) b += bias0[cg * 8 + c];
        if (bias1) b += bias1[cg * 8 + c];
        b01[c] = b;
        gl[c] = g_ln[cg * 8 + c];
        bb[c] = b_ln[cg * 8 + c];
    }

    #pragma unroll
    for (int q = 0; q < 8; ++q) {
        int gr = row0 + rg * 8 + q;
        bool valid = gr < M;
        float v[8];
        if (valid) {
            float rr[8] = {0.f, 0.f, 0.f, 0.f, 0.f, 0.f, 0.f, 0.f};
            if (res) {
                float4 r0 = *(const float4*)(res + (size_t)gr * HD + cg * 8);
                float4 r1 = *(const float4*)(res + (size_t)gr * HD + cg * 8 + 4);
                rr[0] = r0.x; rr[1] = r0.y; rr[2] = r0.z; rr[3] = r0.w;
                rr[4] = r1.x; rr[5] = r1.y; rr[6] = r1.z; rr[7] = r1.w;
            }
            #pragma unroll
            for (int c = 0; c < 8; ++c) v[c] = (acc[q][c] + b01[c]) * scale + rr[c];
        } else {
            #pragma unroll
            for (int c = 0; c < 8; ++c) v[c] = 0.f;
        }
        float s = 0.f, s2 = 0.f;
        #pragma unroll
        for (int c = 0; c < 8; ++c) { s += v[c]; s2 += v[c] * v[c]; }
        #pragma unroll
        for (int m = 1; m <= 8; m <<= 1) {
            s  += __shfl_xor(s, m);
            s2 += __shfl_xor(s2, m);
        }
        float mean = s * (1.f / 128.f);
        float var  = s2 * (1.f / 128.f) - mean * mean;
        float rstd = rsqrtf(var + 1e-5f);
        if (valid) {
            float o[8];
            #pragma unroll
            for (int c = 0; c < 8; ++c) {
                float t = (v[c] - mean) * rstd * gl[c] + bb[c];
                o[c] = gelu_f(t);
            }
            float4 o0 = make_float4(o[0], o[1], o[2], o[3]);
            float4 o1 = make_float4(o[4], o[5], o[6], o[7]);
            *(float4*)(out + (size_t)gr * HD + cg * 8)     = o0;
            *(float4*)(out + (size_t)gr * HD + cg * 8 + 4) = o1;
        }
    }
}

// scatter-add src features into per-dst sum + count (32 lanes per edge, float4 each)
__global__ void scatter_sum(const int* __restrict__ ei, int E,
                            const float* __restrict__ src,
                            float* __restrict__ agg, int* __restrict__ cnt)
{
    int t = blockIdx.x * blockDim.x + threadIdx.x;
    int e = t >> 5;
    if (e >= E) return;
    int lane = t & 31;
    int s = ei[e];
    int d = ei[E + e];
    const float4 v = *(const float4*)(src + (size_t)s * HD + lane * 4);
    float* dp = agg + (size_t)d * HD + lane * 4;
    atomicAdd(dp + 0, v.x);
    atomicAdd(dp + 1, v.y);
    atomicAdd(dp + 2, v.z);
    atomicAdd(dp + 3, v.w);
    if (lane == 0) atomicAdd(cnt + d, 1);
}

// out[e] = dot(P[src[e]], hd[dst[e]])  -- 16 lanes per edge
__global__ void edge_score(const int* __restrict__ ei, int E,
                           const float* __restrict__ P, const float* __restrict__ hdv,
                           float* __restrict__ out)
{
    int t = blockIdx.x * blockDim.x + threadIdx.x;
    int e = t >> 4;
    if (e >= E) return;
    int lane = t & 15;
    int s = ei[e];
    int d = ei[E + e];
    const float4 p0 = *(const float4*)(P + (size_t)s * HD + lane * 8);
    const float4 p1 = *(const float4*)(P + (size_t)s * HD + lane * 8 + 4);
    const float4 h0 = *(const float4*)(hdv + (size_t)d * HD + lane * 8);
    const float4 h1 = *(const float4*)(hdv + (size_t)d * HD + lane * 8 + 4);
    float acc = p0.x * h0.x + p0.y * h0.y + p0.z * h0.z + p0.w * h0.w
              + p1.x * h1.x + p1.y * h1.y + p1.z * h1.z + p1.w * h1.w;
    #pragma unroll
    for (int m = 1; m <= 8; m <<= 1) acc += __shfl_xor(acc, m);
    if (lane == 0) out[e] = acc;
}

extern "C" void kernel_launch(void* const* d_in, const int* in_sizes, int n_in,
                              void* d_out, int out_size, void* d_ws, size_t ws_size,
                              hipStream_t stream)
{
    const float* x_chem    = (const float*)d_in[0];
    const float* x_dis     = (const float*)d_in[1];
    const float* gene_emb  = (const float*)d_in[2];
    const float* proj_W    = (const float*)d_in[3];   // [2][128][128]
    const float* proj_b    = (const float*)d_in[4];   // [2][128]
    const float* proj_ln_g = (const float*)d_in[5];
    const float* proj_ln_b = (const float*)d_in[6];
    const float* sage_Wl   = (const float*)d_in[7];   // [2][4][128][128]
    const float* sage_bl   = (const float*)d_in[8];   // [2][4][128]
    const float* sage_Wr   = (const float*)d_in[9];
    const float* ln_g      = (const float*)d_in[10];  // [2][3][128]
    const float* ln_b      = (const float*)d_in[11];
    const float* W_cd      = (const float*)d_in[12];
    const int*   ei_c2d    = (const int*)d_in[13];
    const int*   ei_d2c    = (const int*)d_in[14];
    const int*   ei_c2g    = (const int*)d_in[15];
    const int*   ei_g2c    = (const int*)d_in[16];
    const int*   pos_edge  = (const int*)d_in[17];
    const int*   neg_edge  = (const int*)d_in[18];
    float* out = (float*)d_out;

    // ---- workspace layout ----
    float* ws    = (float*)d_ws;
    float* hc    = ws;                        // NC*128
    float* hd    = hc    + (size_t)T_NC * HD; // ND*128
    float* hg    = hd    + (size_t)T_ND * HD; // NG*128
    float* aggDC = hg    + (size_t)T_NG * HD; // NC*128 (reused as P at the end)
    float* aggGC = aggDC + (size_t)T_NC * HD; // NC*128
    float* aggCD = aggGC + (size_t)T_NC * HD; // ND*128
    float* aggCG = aggCD + (size_t)T_ND * HD; // NG*128
    int*   cntDC = (int*)(aggCG + (size_t)T_NG * HD);
    int*   cntGC = cntDC + T_NC;
    int*   cntCD = cntGC + T_NC;
    int*   cntCG = cntCD + T_ND;
    float* P     = aggDC;
    const size_t zero_bytes = ((size_t)(2 * T_NC + T_ND + T_NG) * HD) * sizeof(float)
                            + (size_t)(2 * T_NC + T_ND + T_NG) * sizeof(int);

    const dim3 blk(256);
    const int gC = (T_NC + 127) / 128;
    const int gD = (T_ND + 127) / 128;
    const int gG = (T_NG + 127) / 128;
    const int gScat = (T_E * 32 + 255) / 256;
    const int gEdge = (T_EP * 16 + 255) / 256;

    // hg = gene_emb
    hipMemcpyAsync(hg, gene_emb, (size_t)T_NG * HD * sizeof(float),
                   hipMemcpyDeviceToDevice, stream);

    // projections: hc / hd
    gemm_fused<1, true><<<gC, blk, 0, stream>>>(
        x_chem, proj_W, nullptr,  nullptr, nullptr, nullptr,
        nullptr, nullptr, nullptr, nullptr, nullptr, nullptr,
        proj_b, nullptr, 1.f, nullptr, proj_ln_g, proj_ln_b, hc, T_NC);
    gemm_fused<1, true><<<gD, blk, 0, stream>>>(
        x_dis, proj_W + 128 * 128, nullptr,  nullptr, nullptr, nullptr,
        nullptr, nullptr, nullptr, nullptr, nullptr, nullptr,
        proj_b + HD, nullptr, 1.f, nullptr, proj_ln_g + HD, proj_ln_b + HD, hd, T_ND);

    for (int l = 0; l < 2; ++l) {
        const float* Wl = sage_Wl + (size_t)l * 4 * HD * HD;
        const float* Wr = sage_Wr + (size_t)l * 4 * HD * HD;
        const float* bl = sage_bl + (size_t)l * 4 * HD;
        const float* lg = ln_g + (size_t)l * 3 * HD;
        const float* lb = ln_b + (size_t)l * 3 * HD;

        hipMemsetAsync(aggDC, 0, zero_bytes, stream);

        scatter_sum<<<gScat, blk, 0, stream>>>(ei_d2c, T_E, hd, aggDC, cntDC);
        scatter_sum<<<gScat, blk, 0, stream>>>(ei_g2c, T_E, hg, aggGC, cntGC);
        scatter_sum<<<gScat, blk, 0, stream>>>(ei_c2d, T_E, hc, aggCD, cntCD);
        scatter_sum<<<gScat, blk, 0, stream>>>(ei_c2g, T_E, hc, aggCG, cntCG);

        // chem: 0.5*(aggDC@Wl1 + bl1 + hc@Wr1 + aggGC@Wl3 + bl3 + hc@Wr3) + hc -> LN -> GELU
        gemm_fused<4, true><<<gC, blk, 0, stream>>>(
            aggDC, Wl + 1 * HD * HD, cntDC,
            hc,    Wr + 1 * HD * HD, nullptr,
            aggGC, Wl + 3 * HD * HD, cntGC,
            hc,    Wr + 3 * HD * HD, nullptr,
            bl + 1 * HD, bl + 3 * HD, 0.5f, hc, lg + 0 * HD, lb + 0 * HD, hc, T_NC);
        // dis
        gemm_fused<2, true><<<gD, blk, 0, stream>>>(
            aggCD, Wl + 0 * HD * HD, cntCD,
            hd,    Wr + 0 * HD * HD, nullptr,
            nullptr, nullptr, nullptr, nullptr, nullptr, nullptr,
            bl + 0 * HD, nullptr, 1.f, hd, lg + 1 * HD, lb + 1 * HD, hd, T_ND);
        // gene
        gemm_fused<2, true><<<gG, blk, 0, stream>>>(
            aggCG, Wl + 2 * HD * HD, cntCG,
            hg,    Wr + 2 * HD * HD, nullptr,
            nullptr, nullptr, nullptr, nullptr, nullptr, nullptr,
            bl + 2 * HD, nullptr, 1.f, hg, lg + 2 * HD, lb + 2 * HD, hg, T_NG);
    }

    // P = hc @ W_cd
    gemm_fused<1, false><<<gC, blk, 0, stream>>>(
        hc, W_cd, nullptr,  nullptr, nullptr, nullptr,
        nullptr, nullptr, nullptr, nullptr, nullptr, nullptr,
        nullptr, nullptr, 1.f, nullptr, nullptr, nullptr, P, T_NC);

    edge_score<<<gEdge, blk, 0, stream>>>(pos_edge, T_EP, P, hd, out);
    edge_score<<<gEdge, blk, 0, stream>>>(neg_edge, T_EP, P, hd, out + T_EP);
}

// Round 2
// 2550.266 us; speedup vs baseline: 1.4846x; 1.4846x over previous
//
#include <hip/hip_runtime.h>

#define HD 128

constexpr int T_NC = 100000;
constexpr int T_ND = 20000;
constexpr int T_NG = 50000;
constexpr int T_E  = 150000;
constexpr int T_EP = 100000;
constexpr int NMAT = 19;          // packed weight matrices

typedef __attribute__((ext_vector_type(8))) short   s16x8;
typedef __attribute__((ext_vector_type(8))) __bf16  bf16x8;
typedef __attribute__((ext_vector_type(4))) float   f32x4;

union Frag { s16x8 s; bf16x8 b; };

__device__ __forceinline__ float gelu_f(float x) {
    return 0.5f * x * (1.0f + erff(x * 0.70710678118654752f));
}

__device__ __forceinline__ unsigned short bf16_rne(float x) {
    union { float f; unsigned int u; } c; c.f = x;
    unsigned int u = c.u;
    unsigned int r = (u + 0x7fffu + ((u >> 16) & 1u)) >> 16;
    return (unsigned short)r;
}
__device__ __forceinline__ float bf16_to_f(unsigned short h) {
    union { unsigned int u; float f; } c; c.u = ((unsigned int)h) << 16;
    return c.f;
}

// Pre-pack all 19 weight matrices (128x128 fp32) into MFMA B-fragment order,
// bf16 hi + bf16 lo (3-term split). Layout:
//   off = (((mat*8 + colblk)*4 + kstep)*64 + lane)*8 + j
//   element = W[kstep*32 + (lane>>4)*8 + j][colblk*16 + (lane&15)]
__global__ void pack_weights(const float* __restrict__ proj_W,
                             const float* __restrict__ sage_Wl,
                             const float* __restrict__ sage_Wr,
                             const float* __restrict__ W_cd,
                             unsigned short* __restrict__ phi,
                             unsigned short* __restrict__ plo)
{
    int m = blockIdx.x;
    const float* W;
    if (m < 2)       W = proj_W  + (size_t)m * HD * HD;
    else if (m < 10) W = sage_Wl + (size_t)(m - 2) * HD * HD;
    else if (m < 18) W = sage_Wr + (size_t)(m - 10) * HD * HD;
    else             W = W_cd;

    int t = threadIdx.x;          // 256
    int kstep = t >> 6;
    int lane  = t & 63;
    int kbase = kstep * 32 + (lane >> 4) * 8;
    int c     = lane & 15;
    for (int cb = 0; cb < 8; ++cb) {
        int col = cb * 16 + c;
        size_t off = ((((size_t)m * 8 + cb) * 4 + kstep) * 64 + lane) * 8;
        #pragma unroll
        for (int j = 0; j < 8; ++j) {
            float w = W[(size_t)(kbase + j) * HD + col];
            unsigned short h = bf16_rne(w);
            phi[off + j] = h;
            plo[off + j] = bf16_rne(w - bf16_to_f(h));
        }
    }
}

// Fused multi-pair GEMM: acc[r][c] = sum_p A_p[r][:] @ W_p[:][c]  (K=128)
// A rows optionally scaled 1/max(cnt,1).  3-term bf16 split MFMA (16x16x32).
// MODE 1: v=(acc+bias0+bias1)*scale+res, row-LayerNorm, GELU.  MODE 0: store acc.
// Block: 256 thr (4 waves), tile 64 rows x 128 cols; wave w owns cols [w*32,w*32+32).
template<int NP, int MODE>
__global__ __launch_bounds__(256, 4)
void gemm_mfma(const float* __restrict__ A0, const int* __restrict__ c0, int w0,
               const float* __restrict__ A1, const int* __restrict__ c1, int w1,
               const float* __restrict__ A2, const int* __restrict__ c2, int w2,
               const float* __restrict__ A3, const int* __restrict__ c3, int w3,
               const unsigned short* __restrict__ phi, const unsigned short* __restrict__ plo,
               const float* __restrict__ bias0, const float* __restrict__ bias1,
               float scale, const float* __restrict__ res,
               const float* __restrict__ g_ln, const float* __restrict__ b_ln,
               float* __restrict__ out, int M)
{
    __shared__ __align__(16) unsigned short As_hi[64 * HD];
    __shared__ __align__(16) unsigned short As_lo[64 * HD];
    __shared__ float psum[4][64];
    __shared__ float psq[4][64];

    const int tid  = threadIdx.x;
    const int w    = tid >> 6;
    const int lane = tid & 63;
    const int c    = lane & 15;
    const int hi4  = lane >> 4;
    const int row0 = blockIdx.x * 64;

    f32x4 acc[4][2];
    #pragma unroll
    for (int rb = 0; rb < 4; ++rb)
        #pragma unroll
        for (int q = 0; q < 2; ++q) acc[rb][q] = (f32x4)0.f;

    #pragma unroll
    for (int p = 0; p < NP; ++p) {
        const float* A = (p == 0) ? A0 : (p == 1) ? A1 : (p == 2) ? A2 : A3;
        const int*  cp = (p == 0) ? c0 : (p == 1) ? c1 : (p == 2) ? c2 : c3;
        const int widx = (p == 0) ? w0 : (p == 1) ? w1 : (p == 2) ? w2 : w3;

        __syncthreads();   // protect LDS reuse from previous pair
        // ---- stage A tile: fp32 global -> bf16 hi/lo LDS (swizzled) ----
        #pragma unroll
        for (int it = 0; it < 4; ++it) {
            int u  = tid + it * 256;
            int r  = u >> 4;
            int k8 = (u & 15) * 8;
            int gr = row0 + r;
            float v[8];
            #pragma unroll
            for (int j = 0; j < 8; ++j) v[j] = 0.f;
            float rs = 1.f;
            if (gr < M) {
                const float4* ap = (const float4*)(A + (size_t)gr * HD + k8);
                float4 a0 = ap[0], a1 = ap[1];
                v[0] = a0.x; v[1] = a0.y; v[2] = a0.z; v[3] = a0.w;
                v[4] = a1.x; v[5] = a1.y; v[6] = a1.z; v[7] = a1.w;
                if (cp) { int cv = cp[gr]; rs = 1.f / (float)(cv > 1 ? cv : 1); }
            }
            s16x8 vh, vl;
            #pragma unroll
            for (int j = 0; j < 8; ++j) {
                float x = v[j] * rs;
                unsigned short h = bf16_rne(x);
                vh[j] = (short)h;
                vl[j] = (short)bf16_rne(x - bf16_to_f(h));
            }
            int sidx = (r * HD + k8) ^ ((r & 7) << 3);
            *(s16x8*)(As_hi + sidx) = vh;
            *(s16x8*)(As_lo + sidx) = vl;
        }
        __syncthreads();

        // ---- MFMA over 4 k-steps ----
        #pragma unroll
        for (int ks = 0; ks < 4; ++ks) {
            Frag bh[2], bl[2];
            #pragma unroll
            for (int q = 0; q < 2; ++q) {
                int cbG = w * 2 + q;
                size_t boff = ((((size_t)widx * 8 + cbG) * 4 + ks) * 64 + lane) * 8;
                bh[q].s = *(const s16x8*)(phi + boff);
                bl[q].s = *(const s16x8*)(plo + boff);
            }
            #pragma unroll
            for (int rb = 0; rb < 4; ++rb) {
                int r = rb * 16 + c;
                int sidx = (r * HD + ks * 32 + hi4 * 8) ^ ((r & 7) << 3);
                Frag ah, al;
                ah.s = *(const s16x8*)(As_hi + sidx);
                al.s = *(const s16x8*)(As_lo + sidx);
                #pragma unroll
                for (int q = 0; q < 2; ++q) {
                    acc[rb][q] = __builtin_amdgcn_mfma_f32_16x16x32_bf16(ah.b, bh[q].b, acc[rb][q], 0, 0, 0);
                    acc[rb][q] = __builtin_amdgcn_mfma_f32_16x16x32_bf16(al.b, bh[q].b, acc[rb][q], 0, 0, 0);
                    acc[rb][q] = __builtin_amdgcn_mfma_f32_16x16x32_bf16(ah.b, bl[q].b, acc[rb][q], 0, 0, 0);
                }
            }
        }
    }

    // ---- epilogue ----
    // lane layout: col = (w*2+q)*16 + c ; row = rb*16 + hi4*4 + reg
    if (MODE == 0) {
        #pragma unroll
        for (int rb = 0; rb < 4; ++rb)
            #pragma unroll
            for (int q = 0; q < 2; ++q) {
                int col = (w * 2 + q) * 16 + c;
                #pragma unroll
                for (int reg = 0; reg < 4; ++reg) {
                    int gr = row0 + rb * 16 + hi4 * 4 + reg;
                    if (gr < M) out[(size_t)gr * HD + col] = acc[rb][q][reg];
                }
            }
        return;
    }

    float bsum[2], gl[2], bb[2];
    #pragma unroll
    for (int q = 0; q < 2; ++q) {
        int col = (w * 2 + q) * 16 + c;
        float b = 0.f;
        if (bias0) b += bias0[col];
        if (bias1) b += bias1[col];
        bsum[q] = b;
        gl[q] = g_ln[col];
        bb[q] = b_ln[col];
    }

    float v[4][2][4];
    #pragma unroll
    for (int rb = 0; rb < 4; ++rb)
        #pragma unroll
        for (int q = 0; q < 2; ++q) {
            int col = (w * 2 + q) * 16 + c;
            #pragma unroll
            for (int reg = 0; reg < 4; ++reg) {
                int gr = row0 + rb * 16 + hi4 * 4 + reg;
                float r_ = (res && gr < M) ? res[(size_t)gr * HD + col] : 0.f;
                v[rb][q][reg] = (acc[rb][q][reg] + bsum[q]) * scale + r_;
            }
        }

    // per-row partial sums over this wave's 32 cols
    #pragma unroll
    for (int rb = 0; rb < 4; ++rb)
        #pragma unroll
        for (int reg = 0; reg < 4; ++reg) {
            float s = v[rb][0][reg] + v[rb][1][reg];
            float qq = v[rb][0][reg] * v[rb][0][reg] + v[rb][1][reg] * v[rb][1][reg];
            #pragma unroll
            for (int m = 1; m <= 8; m <<= 1) {
                s  += __shfl_xor(s, m);
                qq += __shfl_xor(qq, m);
            }
            if (c == 0) {
                int row = rb * 16 + hi4 * 4 + reg;
                psum[w][row] = s;
                psq[w][row]  = qq;
            }
        }
    __syncthreads();

    #pragma unroll
    for (int rb = 0; rb < 4; ++rb)
        #pragma unroll
        for (int reg = 0; reg < 4; ++reg) {
            int row = rb * 16 + hi4 * 4 + reg;
            float S  = psum[0][row] + psum[1][row] + psum[2][row] + psum[3][row];
            float Q  = psq[0][row]  + psq[1][row]  + psq[2][row]  + psq[3][row];
            float mean = S * (1.f / 128.f);
            float var  = Q * (1.f / 128.f) - mean * mean;
            float rstd = rsqrtf(var + 1e-5f);
            int gr = row0 + row;
            if (gr < M) {
                #pragma unroll
                for (int q = 0; q < 2; ++q) {
                    int col = (w * 2 + q) * 16 + c;
                    float t = (v[rb][q][reg] - mean) * rstd * gl[q] + bb[q];
                    out[(size_t)gr * HD + col] = gelu_f(t);
                }
            }
        }
}

// scatter-add src features into per-dst sum + count (32 lanes per edge)
__global__ void scatter_sum(const int* __restrict__ ei, int E,
                            const float* __restrict__ src,
                            float* __restrict__ agg, int* __restrict__ cnt)
{
    int t = blockIdx.x * blockDim.x + threadIdx.x;
    int e = t >> 5;
    if (e >= E) return;
    int lane = t & 31;
    int s = ei[e];
    int d = ei[E + e];
    const float4 v = *(const float4*)(src + (size_t)s * HD + lane * 4);
    float* dp = agg + (size_t)d * HD + lane * 4;
    atomicAdd(dp + 0, v.x);
    atomicAdd(dp + 1, v.y);
    atomicAdd(dp + 2, v.z);
    atomicAdd(dp + 3, v.w);
    if (lane == 0) atomicAdd(cnt + d, 1);
}

// out[e] = dot(P[src[e]], hd[dst[e]])  -- 16 lanes per edge
__global__ void edge_score(const int* __restrict__ ei, int E,
                           const float* __restrict__ P, const float* __restrict__ hdv,
                           float* __restrict__ out)
{
    int t = blockIdx.x * blockDim.x + threadIdx.x;
    int e = t >> 4;
    if (e >= E) return;
    int lane = t & 15;
    int s = ei[e];
    int d = ei[E + e];
    const float4 p0 = *(const float4*)(P + (size_t)s * HD + lane * 8);
    const float4 p1 = *(const float4*)(P + (size_t)s * HD + lane * 8 + 4);
    const float4 h0 = *(const float4*)(hdv + (size_t)d * HD + lane * 8);
    const float4 h1 = *(const float4*)(hdv + (size_t)d * HD + lane * 8 + 4);
    float acc = p0.x * h0.x + p0.y * h0.y + p0.z * h0.z + p0.w * h0.w
              + p1.x * h1.x + p1.y * h1.y + p1.z * h1.z + p1.w * h1.w;
    #pragma unroll
    for (int m = 1; m <= 8; m <<= 1) acc += __shfl_xor(acc, m);
    if (lane == 0) out[e] = acc;
}

extern "C" void kernel_launch(void* const* d_in, const int* in_sizes, int n_in,
                              void* d_out, int out_size, void* d_ws, size_t ws_size,
                              hipStream_t stream)
{
    const float* x_chem    = (const float*)d_in[0];
    const float* x_dis     = (const float*)d_in[1];
    const float* gene_emb  = (const float*)d_in[2];
    const float* proj_W    = (const float*)d_in[3];
    const float* proj_b    = (const float*)d_in[4];
    const float* proj_ln_g = (const float*)d_in[5];
    const float* proj_ln_b = (const float*)d_in[6];
    const float* sage_Wl   = (const float*)d_in[7];
    const float* sage_bl   = (const float*)d_in[8];
    const float* sage_Wr   = (const float*)d_in[9];
    const float* ln_g      = (const float*)d_in[10];
    const float* ln_b      = (const float*)d_in[11];
    const float* W_cd      = (const float*)d_in[12];
    const int*   ei_c2d    = (const int*)d_in[13];
    const int*   ei_d2c    = (const int*)d_in[14];
    const int*   ei_c2g    = (const int*)d_in[15];
    const int*   ei_g2c    = (const int*)d_in[16];
    const int*   pos_edge  = (const int*)d_in[17];
    const int*   neg_edge  = (const int*)d_in[18];
    float* out = (float*)d_out;

    // ---- workspace layout ----
    float* ws    = (float*)d_ws;
    float* hc    = ws;
    float* hd    = hc    + (size_t)T_NC * HD;
    float* hg    = hd    + (size_t)T_ND * HD;
    float* aggDC = hg    + (size_t)T_NG * HD;
    float* aggGC = aggDC + (size_t)T_NC * HD;
    float* aggCD = aggGC + (size_t)T_NC * HD;
    float* aggCG = aggCD + (size_t)T_ND * HD;
    int*   cntDC = (int*)(aggCG + (size_t)T_NG * HD);
    int*   cntGC = cntDC + T_NC;
    int*   cntCD = cntGC + T_NC;
    int*   cntCG = cntCD + T_ND;
    unsigned short* packHi = (unsigned short*)(cntCG + T_NG);
    unsigned short* packLo = packHi + (size_t)NMAT * 8 * 4 * 64 * 8;
    float* P = aggDC;  // reuse after last layer
    const size_t zero_bytes = ((size_t)(2 * T_NC + T_ND + T_NG) * HD) * sizeof(float)
                            + (size_t)(2 * T_NC + T_ND + T_NG) * sizeof(int);

    const dim3 blk(256);
    const int gC = (T_NC + 63) / 64;
    const int gD = (T_ND + 63) / 64;
    const int gG = (T_NG + 63) / 64;
    const int gScat = (T_E * 32 + 255) / 256;
    const int gEdge = (T_EP * 16 + 255) / 256;

    pack_weights<<<NMAT, blk, 0, stream>>>(proj_W, sage_Wl, sage_Wr, W_cd, packHi, packLo);

    hipMemcpyAsync(hg, gene_emb, (size_t)T_NG * HD * sizeof(float),
                   hipMemcpyDeviceToDevice, stream);

    // projections
    gemm_mfma<1, 1><<<gC, blk, 0, stream>>>(
        x_chem, nullptr, 0,  nullptr, nullptr, 0,  nullptr, nullptr, 0,  nullptr, nullptr, 0,
        packHi, packLo, proj_b, nullptr, 1.f, nullptr, proj_ln_g, proj_ln_b, hc, T_NC);
    gemm_mfma<1, 1><<<gD, blk, 0, stream>>>(
        x_dis, nullptr, 1,  nullptr, nullptr, 0,  nullptr, nullptr, 0,  nullptr, nullptr, 0,
        packHi, packLo, proj_b + HD, nullptr, 1.f, nullptr, proj_ln_g + HD, proj_ln_b + HD, hd, T_ND);

    for (int l = 0; l < 2; ++l) {
        const float* bl = sage_bl + (size_t)l * 4 * HD;
        const float* lg = ln_g + (size_t)l * 3 * HD;
        const float* lb = ln_b + (size_t)l * 3 * HD;
        const int wl = 2 + l * 4;    // sage_Wl[l][e] -> mat 2 + l*4 + e
        const int wr = 10 + l * 4;   // sage_Wr[l][e] -> mat 10 + l*4 + e

        hipMemsetAsync(aggDC, 0, zero_bytes, stream);

        scatter_sum<<<gScat, blk, 0, stream>>>(ei_d2c, T_E, hd, aggDC, cntDC);
        scatter_sum<<<gScat, blk, 0, stream>>>(ei_g2c, T_E, hg, aggGC, cntGC);
        scatter_sum<<<gScat, blk, 0, stream>>>(ei_c2d, T_E, hc, aggCD, cntCD);
        scatter_sum<<<gScat, blk, 0, stream>>>(ei_c2g, T_E, hc, aggCG, cntCG);

        // chem: 0.5*(aggDC@Wl1 + bl1 + hc@Wr1 + aggGC@Wl3 + bl3 + hc@Wr3) + hc -> LN -> GELU
        gemm_mfma<4, 1><<<gC, blk, 0, stream>>>(
            aggDC, cntDC, wl + 1,
            hc,    nullptr, wr + 1,
            aggGC, cntGC, wl + 3,
            hc,    nullptr, wr + 3,
            packHi, packLo, bl + 1 * HD, bl + 3 * HD, 0.5f, hc, lg + 0 * HD, lb + 0 * HD, hc, T_NC);
        // dis
        gemm_mfma<2, 1><<<gD, blk, 0, stream>>>(
            aggCD, cntCD, wl + 0,
            hd,    nullptr, wr + 0,
            nullptr, nullptr, 0,  nullptr, nullptr, 0,
            packHi, packLo, bl + 0 * HD, nullptr, 1.f, hd, lg + 1 * HD, lb + 1 * HD, hd, T_ND);
        // gene
        gemm_mfma<2, 1><<<gG, blk, 0, stream>>>(
            aggCG, cntCG, wl + 2,
            hg,    nullptr, wr + 2,
            nullptr, nullptr, 0,  nullptr, nullptr, 0,
            packHi, packLo, bl + 2 * HD, nullptr, 1.f, hg, lg + 2 * HD, lb + 2 * HD, hg, T_NG);
    }

    // P = hc @ W_cd
    gemm_mfma<1, 0><<<gC, blk, 0, stream>>>(
        hc, nullptr, 18,  nullptr, nullptr, 0,  nullptr, nullptr, 0,  nullptr, nullptr, 0,
        packHi, packLo, nullptr, nullptr, 1.f, nullptr, nullptr, nullptr, P, T_NC);

    edge_score<<<gEdge, blk, 0, stream>>>(pos_edge, T_EP, P, hd, out);
    edge_score<<<gEdge, blk, 0, stream>>>(neg_edge, T_EP, P, hd, out + T_EP);
}

// Round 3
// 698.525 us; speedup vs baseline: 5.4202x; 3.6509x over previous
//
#include <hip/hip_runtime.h>

#define HD 128

constexpr int T_NC = 100000;
constexpr int T_ND = 20000;
constexpr int T_NG = 50000;
constexpr int T_E  = 150000;
constexpr int T_EP = 100000;
constexpr int NMAT = 19;          // packed weight matrices

typedef __attribute__((ext_vector_type(8))) short   s16x8;
typedef __attribute__((ext_vector_type(8))) __bf16  bf16x8;
typedef __attribute__((ext_vector_type(4))) float   f32x4;

union Frag { s16x8 s; bf16x8 b; };

__device__ __forceinline__ float gelu_f(float x) {
    return 0.5f * x * (1.0f + erff(x * 0.70710678118654752f));
}

__device__ __forceinline__ unsigned short bf16_rne(float x) {
    union { float f; unsigned int u; } c; c.f = x;
    unsigned int u = c.u;
    unsigned int r = (u + 0x7fffu + ((u >> 16) & 1u)) >> 16;
    return (unsigned short)r;
}
__device__ __forceinline__ float bf16_to_f(unsigned short h) {
    union { unsigned int u; float f; } c; c.u = ((unsigned int)h) << 16;
    return c.f;
}

// ---------------- weight packing (once per launch) ----------------
__global__ void pack_weights(const float* __restrict__ proj_W,
                             const float* __restrict__ sage_Wl,
                             const float* __restrict__ sage_Wr,
                             const float* __restrict__ W_cd,
                             unsigned short* __restrict__ phi,
                             unsigned short* __restrict__ plo)
{
    int m = blockIdx.x;
    const float* W;
    if (m < 2)       W = proj_W  + (size_t)m * HD * HD;
    else if (m < 10) W = sage_Wl + (size_t)(m - 2) * HD * HD;
    else if (m < 18) W = sage_Wr + (size_t)(m - 10) * HD * HD;
    else             W = W_cd;

    int t = threadIdx.x;          // 256
    int kstep = t >> 6;
    int lane  = t & 63;
    int kbase = kstep * 32 + (lane >> 4) * 8;
    int c     = lane & 15;
    for (int cb = 0; cb < 8; ++cb) {
        int col = cb * 16 + c;
        size_t off = ((((size_t)m * 8 + cb) * 4 + kstep) * 64 + lane) * 8;
        #pragma unroll
        for (int j = 0; j < 8; ++j) {
            float w = W[(size_t)(kbase + j) * HD + col];
            unsigned short h = bf16_rne(w);
            phi[off + j] = h;
            plo[off + j] = bf16_rne(w - bf16_to_f(h));
        }
    }
}

// ---------------- CSR build (once per launch; edge lists are static) ----------------
__global__ void edge_count(const int* __restrict__ ei, int E, int* __restrict__ deg)
{
    int e = blockIdx.x * blockDim.x + threadIdx.x;
    if (e < E) atomicAdd(&deg[ei[E + e]], 1);
}

// block-local exclusive scan over chunks of 1024 (256 thr x 4 elems)
__global__ void scan_local(const int* __restrict__ deg, int* __restrict__ rp,
                           int* __restrict__ bsum, int N)
{
    __shared__ int wtot[4];
    int t = threadIdx.x;
    int lane = t & 63, w = t >> 6;
    int base = blockIdx.x * 1024 + t * 4;
    int v[4];
    #pragma unroll
    for (int j = 0; j < 4; ++j) v[j] = (base + j < N) ? deg[base + j] : 0;
    int p1 = v[0] + v[1];
    int p2 = p1 + v[2];
    int total = p2 + v[3];
    int sc = total;
    #pragma unroll
    for (int o = 1; o < 64; o <<= 1) {
        int y = __shfl_up(sc, o);
        if (lane >= o) sc += y;
    }
    if (lane == 63) wtot[w] = sc;
    __syncthreads();
    int woff = 0;
    for (int i = 0; i < w; ++i) woff += wtot[i];
    int ex = woff + sc - total;   // exclusive offset of this thread's 4 elems
    if (base + 0 < N) rp[base + 0] = ex;
    if (base + 1 < N) rp[base + 1] = ex + v[0];
    if (base + 2 < N) rp[base + 2] = ex + p1;
    if (base + 3 < N) rp[base + 3] = ex + p2;
    if (t == 255) bsum[blockIdx.x] = woff + sc;
}

__global__ void scan_tops(int* __restrict__ bsum, int B)
{
    int lane = threadIdx.x;  // 64
    int off = 0;
    for (int s = 0; s < B; s += 64) {
        int i = s + lane;
        int v = (i < B) ? bsum[i] : 0;
        int sc = v;
        #pragma unroll
        for (int o = 1; o < 64; o <<= 1) {
            int y = __shfl_up(sc, o);
            if (lane >= o) sc += y;
        }
        if (i < B) bsum[i] = off + sc - v;
        off += __shfl(sc, 63);
    }
}

__global__ void scan_add(int* __restrict__ rp, const int* __restrict__ bsum, int N)
{
    int base = blockIdx.x * 1024 + threadIdx.x * 4;
    int o = bsum[blockIdx.x];
    #pragma unroll
    for (int j = 0; j < 4; ++j)
        if (base + j < N) rp[base + j] += o;
}

__global__ void edge_fill(const int* __restrict__ ei, int E,
                          const int* __restrict__ rp, int* __restrict__ fill,
                          int* __restrict__ col)
{
    int e = blockIdx.x * blockDim.x + threadIdx.x;
    if (e < E) {
        int d = ei[E + e];
        int p = rp[d] + atomicAdd(&fill[d], 1);
        col[p] = ei[e];
    }
}

// ---------------- CSR gather-mean aggregation (per layer) ----------------
// 32 lanes per dst row; register accumulate; one coalesced write.
__global__ void csr_mean_gather(const int* __restrict__ rp, const int* __restrict__ deg,
                                const int* __restrict__ col,
                                const float* __restrict__ src,
                                float* __restrict__ out, int N)
{
    int t = blockIdx.x * blockDim.x + threadIdx.x;
    int r = t >> 5;
    if (r >= N) return;
    int lane = t & 31;
    int start = rp[r];
    int d = deg[r];
    float4 acc = make_float4(0.f, 0.f, 0.f, 0.f);
    for (int i = 0; i < d; ++i) {
        int s = col[start + i];
        const float4 v = *(const float4*)(src + (size_t)s * HD + lane * 4);
        acc.x += v.x; acc.y += v.y; acc.z += v.z; acc.w += v.w;
    }
    float rs = 1.f / (float)(d > 1 ? d : 1);
    acc.x *= rs; acc.y *= rs; acc.z *= rs; acc.w *= rs;
    *(float4*)(out + (size_t)r * HD + lane * 4) = acc;
}

// ---------------- fused multi-pair GEMM (MFMA, 3-term bf16 split) ----------------
template<int NP, int MODE>
__global__ __launch_bounds__(256, 4)
void gemm_mfma(const float* __restrict__ A0, int w0,
               const float* __restrict__ A1, int w1,
               const float* __restrict__ A2, int w2,
               const float* __restrict__ A3, int w3,
               const unsigned short* __restrict__ phi, const unsigned short* __restrict__ plo,
               const float* __restrict__ bias0, const float* __restrict__ bias1,
               float scale, const float* __restrict__ res,
               const float* __restrict__ g_ln, const float* __restrict__ b_ln,
               float* __restrict__ out, int M)
{
    __shared__ __align__(16) unsigned short As_hi[64 * HD];
    __shared__ __align__(16) unsigned short As_lo[64 * HD];
    __shared__ float psum[4][64];
    __shared__ float psq[4][64];

    const int tid  = threadIdx.x;
    const int w    = tid >> 6;
    const int lane = tid & 63;
    const int c    = lane & 15;
    const int hi4  = lane >> 4;
    const int row0 = blockIdx.x * 64;

    f32x4 acc[4][2];
    #pragma unroll
    for (int rb = 0; rb < 4; ++rb)
        #pragma unroll
        for (int q = 0; q < 2; ++q) acc[rb][q] = (f32x4)0.f;

    #pragma unroll
    for (int p = 0; p < NP; ++p) {
        const float* A = (p == 0) ? A0 : (p == 1) ? A1 : (p == 2) ? A2 : A3;
        const int widx = (p == 0) ? w0 : (p == 1) ? w1 : (p == 2) ? w2 : w3;

        __syncthreads();   // protect LDS reuse from previous pair
        #pragma unroll
        for (int it = 0; it < 4; ++it) {
            int u  = tid + it * 256;
            int r  = u >> 4;
            int k8 = (u & 15) * 8;
            int gr = row0 + r;
            float v[8];
            #pragma unroll
            for (int j = 0; j < 8; ++j) v[j] = 0.f;
            if (gr < M) {
                const float4* ap = (const float4*)(A + (size_t)gr * HD + k8);
                float4 a0 = ap[0], a1 = ap[1];
                v[0] = a0.x; v[1] = a0.y; v[2] = a0.z; v[3] = a0.w;
                v[4] = a1.x; v[5] = a1.y; v[6] = a1.z; v[7] = a1.w;
            }
            s16x8 vh, vl;
            #pragma unroll
            for (int j = 0; j < 8; ++j) {
                float x = v[j];
                unsigned short h = bf16_rne(x);
                vh[j] = (short)h;
                vl[j] = (short)bf16_rne(x - bf16_to_f(h));
            }
            int sidx = (r * HD + k8) ^ ((r & 7) << 3);
            *(s16x8*)(As_hi + sidx) = vh;
            *(s16x8*)(As_lo + sidx) = vl;
        }
        __syncthreads();

        #pragma unroll
        for (int ks = 0; ks < 4; ++ks) {
            Frag bh[2], bl[2];
            #pragma unroll
            for (int q = 0; q < 2; ++q) {
                int cbG = w * 2 + q;
                size_t boff = ((((size_t)widx * 8 + cbG) * 4 + ks) * 64 + lane) * 8;
                bh[q].s = *(const s16x8*)(phi + boff);
                bl[q].s = *(const s16x8*)(plo + boff);
            }
            #pragma unroll
            for (int rb = 0; rb < 4; ++rb) {
                int r = rb * 16 + c;
                int sidx = (r * HD + ks * 32 + hi4 * 8) ^ ((r & 7) << 3);
                Frag ah, al;
                ah.s = *(const s16x8*)(As_hi + sidx);
                al.s = *(const s16x8*)(As_lo + sidx);
                #pragma unroll
                for (int q = 0; q < 2; ++q) {
                    acc[rb][q] = __builtin_amdgcn_mfma_f32_16x16x32_bf16(ah.b, bh[q].b, acc[rb][q], 0, 0, 0);
                    acc[rb][q] = __builtin_amdgcn_mfma_f32_16x16x32_bf16(al.b, bh[q].b, acc[rb][q], 0, 0, 0);
                    acc[rb][q] = __builtin_amdgcn_mfma_f32_16x16x32_bf16(ah.b, bl[q].b, acc[rb][q], 0, 0, 0);
                }
            }
        }
    }

    // lane layout: col = (w*2+q)*16 + c ; row = rb*16 + hi4*4 + reg
    if (MODE == 0) {
        #pragma unroll
        for (int rb = 0; rb < 4; ++rb)
            #pragma unroll
            for (int q = 0; q < 2; ++q) {
                int col = (w * 2 + q) * 16 + c;
                #pragma unroll
                for (int reg = 0; reg < 4; ++reg) {
                    int gr = row0 + rb * 16 + hi4 * 4 + reg;
                    if (gr < M) out[(size_t)gr * HD + col] = acc[rb][q][reg];
                }
            }
        return;
    }

    float bsum_[2], gl[2], bb[2];
    #pragma unroll
    for (int q = 0; q < 2; ++q) {
        int col = (w * 2 + q) * 16 + c;
        float b = 0.f;
        if (bias0) b += bias0[col];
        if (bias1) b += bias1[col];
        bsum_[q] = b;
        gl[q] = g_ln[col];
        bb[q] = b_ln[col];
    }

    float v[4][2][4];
    #pragma unroll
    for (int rb = 0; rb < 4; ++rb)
        #pragma unroll
        for (int q = 0; q < 2; ++q) {
            int col = (w * 2 + q) * 16 + c;
            #pragma unroll
            for (int reg = 0; reg < 4; ++reg) {
                int gr = row0 + rb * 16 + hi4 * 4 + reg;
                float r_ = (res && gr < M) ? res[(size_t)gr * HD + col] : 0.f;
                v[rb][q][reg] = (acc[rb][q][reg] + bsum_[q]) * scale + r_;
            }
        }

    #pragma unroll
    for (int rb = 0; rb < 4; ++rb)
        #pragma unroll
        for (int reg = 0; reg < 4; ++reg) {
            float s = v[rb][0][reg] + v[rb][1][reg];
            float qq = v[rb][0][reg] * v[rb][0][reg] + v[rb][1][reg] * v[rb][1][reg];
            #pragma unroll
            for (int m = 1; m <= 8; m <<= 1) {
                s  += __shfl_xor(s, m);
                qq += __shfl_xor(qq, m);
            }
            if (c == 0) {
                int row = rb * 16 + hi4 * 4 + reg;
                psum[w][row] = s;
                psq[w][row]  = qq;
            }
        }
    __syncthreads();

    #pragma unroll
    for (int rb = 0; rb < 4; ++rb)
        #pragma unroll
        for (int reg = 0; reg < 4; ++reg) {
            int row = rb * 16 + hi4 * 4 + reg;
            float S  = psum[0][row] + psum[1][row] + psum[2][row] + psum[3][row];
            float Q  = psq[0][row]  + psq[1][row]  + psq[2][row]  + psq[3][row];
            float mean = S * (1.f / 128.f);
            float var  = Q * (1.f / 128.f) - mean * mean;
            float rstd = rsqrtf(var + 1e-5f);
            int gr = row0 + row;
            if (gr < M) {
                #pragma unroll
                for (int q = 0; q < 2; ++q) {
                    int col = (w * 2 + q) * 16 + c;
                    float t = (v[rb][q][reg] - mean) * rstd * gl[q] + bb[q];
                    out[(size_t)gr * HD + col] = gelu_f(t);
                }
            }
        }
}

// out[e] = dot(P[src[e]], hd[dst[e]])  -- 16 lanes per edge
__global__ void edge_score(const int* __restrict__ ei, int E,
                           const float* __restrict__ P, const float* __restrict__ hdv,
                           float* __restrict__ out)
{
    int t = blockIdx.x * blockDim.x + threadIdx.x;
    int e = t >> 4;
    if (e >= E) return;
    int lane = t & 15;
    int s = ei[e];
    int d = ei[E + e];
    const float4 p0 = *(const float4*)(P + (size_t)s * HD + lane * 8);
    const float4 p1 = *(const float4*)(P + (size_t)s * HD + lane * 8 + 4);
    const float4 h0 = *(const float4*)(hdv + (size_t)d * HD + lane * 8);
    const float4 h1 = *(const float4*)(hdv + (size_t)d * HD + lane * 8 + 4);
    float acc = p0.x * h0.x + p0.y * h0.y + p0.z * h0.z + p0.w * h0.w
              + p1.x * h1.x + p1.y * h1.y + p1.z * h1.z + p1.w * h1.w;
    #pragma unroll
    for (int m = 1; m <= 8; m <<= 1) acc += __shfl_xor(acc, m);
    if (lane == 0) out[e] = acc;
}

extern "C" void kernel_launch(void* const* d_in, const int* in_sizes, int n_in,
                              void* d_out, int out_size, void* d_ws, size_t ws_size,
                              hipStream_t stream)
{
    const float* x_chem    = (const float*)d_in[0];
    const float* x_dis     = (const float*)d_in[1];
    const float* gene_emb  = (const float*)d_in[2];
    const float* proj_W    = (const float*)d_in[3];
    const float* proj_b    = (const float*)d_in[4];
    const float* proj_ln_g = (const float*)d_in[5];
    const float* proj_ln_b = (const float*)d_in[6];
    const float* sage_Wl   = (const float*)d_in[7];
    const float* sage_bl   = (const float*)d_in[8];
    const float* sage_Wr   = (const float*)d_in[9];
    const float* ln_g      = (const float*)d_in[10];
    const float* ln_b      = (const float*)d_in[11];
    const float* W_cd      = (const float*)d_in[12];
    const int*   ei_c2d    = (const int*)d_in[13];
    const int*   ei_d2c    = (const int*)d_in[14];
    const int*   ei_c2g    = (const int*)d_in[15];
    const int*   ei_g2c    = (const int*)d_in[16];
    const int*   pos_edge  = (const int*)d_in[17];
    const int*   neg_edge  = (const int*)d_in[18];
    float* out = (float*)d_out;

    // ---- workspace layout ----
    float* ws    = (float*)d_ws;
    float* hc    = ws;
    float* hd    = hc    + (size_t)T_NC * HD;
    float* hg    = hd    + (size_t)T_ND * HD;
    float* aggDC = hg    + (size_t)T_NG * HD;
    float* aggGC = aggDC + (size_t)T_NC * HD;
    float* aggCD = aggGC + (size_t)T_NC * HD;
    float* aggCG = aggCD + (size_t)T_ND * HD;
    unsigned short* packHi = (unsigned short*)(aggCG + (size_t)T_NG * HD);
    unsigned short* packLo = packHi + (size_t)NMAT * HD * HD;
    int* ib = (int*)(packLo + (size_t)NMAT * HD * HD);
    // degree region (contiguous, zeroed once)
    int* deg_dc = ib;               // NC
    int* deg_gc = deg_dc + T_NC;    // NC
    int* deg_cd = deg_gc + T_NC;    // ND
    int* deg_cg = deg_cd + T_ND;    // NG
    // fill region (contiguous, zeroed once)
    int* fil_dc = deg_cg + T_NG;
    int* fil_gc = fil_dc + T_NC;
    int* fil_cd = fil_gc + T_NC;
    int* fil_cg = fil_cd + T_ND;
    // row_ptr region
    int* rp_dc  = fil_cg + T_NG;
    int* rp_gc  = rp_dc + T_NC;
    int* rp_cd  = rp_gc + T_NC;
    int* rp_cg  = rp_cd + T_ND;
    // col arrays
    int* col_dc = rp_cg + T_NG;
    int* col_gc = col_dc + T_E;
    int* col_cd = col_gc + T_E;
    int* col_cg = col_cd + T_E;
    int* bsum   = col_cg + T_E;     // 256
    float* P = aggDC;               // reuse after last layer

    const dim3 blk(256);
    const int gC = (T_NC + 63) / 64;
    const int gD = (T_ND + 63) / 64;
    const int gG = (T_NG + 63) / 64;
    const int gE256 = (T_E + 255) / 256;
    const int gEdge = (T_EP * 16 + 255) / 256;
    const int DEGN = 2 * T_NC + T_ND + T_NG;

    // ---- one-time: pack weights, init hg, build 4 CSRs ----
    pack_weights<<<NMAT, blk, 0, stream>>>(proj_W, sage_Wl, sage_Wr, W_cd, packHi, packLo);
    hipMemcpyAsync(hg, gene_emb, (size_t)T_NG * HD * sizeof(float),
                   hipMemcpyDeviceToDevice, stream);
    hipMemsetAsync(deg_dc, 0, (size_t)2 * DEGN * sizeof(int), stream);  // deg + fill regions

    edge_count<<<gE256, blk, 0, stream>>>(ei_d2c, T_E, deg_dc);
    edge_count<<<gE256, blk, 0, stream>>>(ei_g2c, T_E, deg_gc);
    edge_count<<<gE256, blk, 0, stream>>>(ei_c2d, T_E, deg_cd);
    edge_count<<<gE256, blk, 0, stream>>>(ei_c2g, T_E, deg_cg);

    struct { const int* deg; int* rp; int n; } scans[4] = {
        {deg_dc, rp_dc, T_NC}, {deg_gc, rp_gc, T_NC},
        {deg_cd, rp_cd, T_ND}, {deg_cg, rp_cg, T_NG}};
    for (int i = 0; i < 4; ++i) {
        int B = (scans[i].n + 1023) / 1024;
        scan_local<<<B, blk, 0, stream>>>(scans[i].deg, scans[i].rp, bsum, scans[i].n);
        scan_tops<<<1, 64, 0, stream>>>(bsum, B);
        scan_add<<<B, blk, 0, stream>>>(scans[i].rp, bsum, scans[i].n);
    }

    edge_fill<<<gE256, blk, 0, stream>>>(ei_d2c, T_E, rp_dc, fil_dc, col_dc);
    edge_fill<<<gE256, blk, 0, stream>>>(ei_g2c, T_E, rp_gc, fil_gc, col_gc);
    edge_fill<<<gE256, blk, 0, stream>>>(ei_c2d, T_E, rp_cd, fil_cd, col_cd);
    edge_fill<<<gE256, blk, 0, stream>>>(ei_c2g, T_E, rp_cg, fil_cg, col_cg);

    // ---- projections ----
    gemm_mfma<1, 1><<<gC, blk, 0, stream>>>(
        x_chem, 0,  nullptr, 0,  nullptr, 0,  nullptr, 0,
        packHi, packLo, proj_b, nullptr, 1.f, nullptr, proj_ln_g, proj_ln_b, hc, T_NC);
    gemm_mfma<1, 1><<<gD, blk, 0, stream>>>(
        x_dis, 1,  nullptr, 0,  nullptr, 0,  nullptr, 0,
        packHi, packLo, proj_b + HD, nullptr, 1.f, nullptr, proj_ln_g + HD, proj_ln_b + HD, hd, T_ND);

    const int gAggC = (T_NC * 32 + 255) / 256;
    const int gAggD = (T_ND * 32 + 255) / 256;
    const int gAggG = (T_NG * 32 + 255) / 256;

    for (int l = 0; l < 2; ++l) {
        const float* bl = sage_bl + (size_t)l * 4 * HD;
        const float* lg = ln_g + (size_t)l * 3 * HD;
        const float* lb = ln_b + (size_t)l * 3 * HD;
        const int wl = 2 + l * 4;
        const int wr = 10 + l * 4;

        csr_mean_gather<<<gAggC, blk, 0, stream>>>(rp_dc, deg_dc, col_dc, hd, aggDC, T_NC);
        csr_mean_gather<<<gAggC, blk, 0, stream>>>(rp_gc, deg_gc, col_gc, hg, aggGC, T_NC);
        csr_mean_gather<<<gAggD, blk, 0, stream>>>(rp_cd, deg_cd, col_cd, hc, aggCD, T_ND);
        csr_mean_gather<<<gAggG, blk, 0, stream>>>(rp_cg, deg_cg, col_cg, hc, aggCG, T_NG);

        gemm_mfma<4, 1><<<gC, blk, 0, stream>>>(
            aggDC, wl + 1,
            hc,    wr + 1,
            aggGC, wl + 3,
            hc,    wr + 3,
            packHi, packLo, bl + 1 * HD, bl + 3 * HD, 0.5f, hc, lg + 0 * HD, lb + 0 * HD, hc, T_NC);
        gemm_mfma<2, 1><<<gD, blk, 0, stream>>>(
            aggCD, wl + 0,
            hd,    wr + 0,
            nullptr, 0,  nullptr, 0,
            packHi, packLo, bl + 0 * HD, nullptr, 1.f, hd, lg + 1 * HD, lb + 1 * HD, hd, T_ND);
        gemm_mfma<2, 1><<<gG, blk, 0, stream>>>(
            aggCG, wl + 2,
            hg,    wr + 2,
            nullptr, 0,  nullptr, 0,
            packHi, packLo, bl + 2 * HD, nullptr, 1.f, hg, lg + 2 * HD, lb + 2 * HD, hg, T_NG);
    }

    // P = hc @ W_cd
    gemm_mfma<1, 0><<<gC, blk, 0, stream>>>(
        hc, 18,  nullptr, 0,  nullptr, 0,  nullptr, 0,
        packHi, packLo, nullptr, nullptr, 1.f, nullptr, nullptr, nullptr, P, T_NC);

    edge_score<<<gEdge, blk, 0, stream>>>(pos_edge, T_EP, P, hd, out);
    edge_score<<<gEdge, blk, 0, stream>>>(neg_edge, T_EP, P, hd, out + T_EP);
}

// Round 4
// 616.665 us; speedup vs baseline: 6.1397x; 1.1327x over previous
//
#include <hip/hip_runtime.h>

#define HD 128

constexpr int T_NC = 100000;
constexpr int T_ND = 20000;
constexpr int T_NG = 50000;
constexpr int T_E  = 150000;
constexpr int T_EP = 100000;
constexpr int NMAT = 21;          // 2 proj + 8 Wl + 8 Wr + W_cd + 2 summed (Wr1+Wr3 per layer)

typedef __attribute__((ext_vector_type(8))) short   s16x8;
typedef __attribute__((ext_vector_type(8))) __bf16  bf16x8;
typedef __attribute__((ext_vector_type(4))) float   f32x4;

union Frag { s16x8 s; bf16x8 b; };

__device__ __forceinline__ float gelu_f(float x) {
    return 0.5f * x * (1.0f + erff(x * 0.70710678118654752f));
}

__device__ __forceinline__ unsigned short bf16_rne(float x) {
    union { float f; unsigned int u; } c; c.f = x;
    unsigned int u = c.u;
    unsigned int r = (u + 0x7fffu + ((u >> 16) & 1u)) >> 16;
    return (unsigned short)r;
}
__device__ __forceinline__ float bf16_to_f(unsigned short h) {
    union { unsigned int u; float f; } c; c.u = ((unsigned int)h) << 16;
    return c.f;
}

// ---------------- weight packing (once per launch) ----------------
// mats: 0-1 proj, 2-9 sage_Wl[l][e], 10-17 sage_Wr[l][e], 18 W_cd,
//       19-20: sage_Wr[l][1]+sage_Wr[l][3]  (chem right-matrix merged)
__global__ void pack_weights(const float* __restrict__ proj_W,
                             const float* __restrict__ sage_Wl,
                             const float* __restrict__ sage_Wr,
                             const float* __restrict__ W_cd,
                             unsigned short* __restrict__ phi,
                             unsigned short* __restrict__ plo)
{
    int m = blockIdx.x;
    const float* W;
    const float* W2 = nullptr;
    if (m < 2)        W = proj_W  + (size_t)m * HD * HD;
    else if (m < 10)  W = sage_Wl + (size_t)(m - 2) * HD * HD;
    else if (m < 18)  W = sage_Wr + (size_t)(m - 10) * HD * HD;
    else if (m == 18) W = W_cd;
    else {
        int l = m - 19;
        W  = sage_Wr + (size_t)(l * 4 + 1) * HD * HD;
        W2 = sage_Wr + (size_t)(l * 4 + 3) * HD * HD;
    }

    int t = threadIdx.x;          // 256
    int kstep = t >> 6;
    int lane  = t & 63;
    int kbase = kstep * 32 + (lane >> 4) * 8;
    int c     = lane & 15;
    for (int cb = 0; cb < 8; ++cb) {
        int col = cb * 16 + c;
        size_t off = ((((size_t)m * 8 + cb) * 4 + kstep) * 64 + lane) * 8;
        #pragma unroll
        for (int j = 0; j < 8; ++j) {
            float w = W[(size_t)(kbase + j) * HD + col];
            if (W2) w += W2[(size_t)(kbase + j) * HD + col];
            unsigned short h = bf16_rne(w);
            phi[off + j] = h;
            plo[off + j] = bf16_rne(w - bf16_to_f(h));
        }
    }
}

// ---------------- CSR build (once per launch; edge lists are static) ----------------
__global__ void edge_count(const int* __restrict__ ei, int E, int* __restrict__ deg)
{
    int e = blockIdx.x * blockDim.x + threadIdx.x;
    if (e < E) atomicAdd(&deg[ei[E + e]], 1);
}

__global__ void scan_local(const int* __restrict__ deg, int* __restrict__ rp,
                           int* __restrict__ bsum, int N)
{
    __shared__ int wtot[4];
    int t = threadIdx.x;
    int lane = t & 63, w = t >> 6;
    int base = blockIdx.x * 1024 + t * 4;
    int v[4];
    #pragma unroll
    for (int j = 0; j < 4; ++j) v[j] = (base + j < N) ? deg[base + j] : 0;
    int p1 = v[0] + v[1];
    int p2 = p1 + v[2];
    int total = p2 + v[3];
    int sc = total;
    #pragma unroll
    for (int o = 1; o < 64; o <<= 1) {
        int y = __shfl_up(sc, o);
        if (lane >= o) sc += y;
    }
    if (lane == 63) wtot[w] = sc;
    __syncthreads();
    int woff = 0;
    for (int i = 0; i < w; ++i) woff += wtot[i];
    int ex = woff + sc - total;
    if (base + 0 < N) rp[base + 0] = ex;
    if (base + 1 < N) rp[base + 1] = ex + v[0];
    if (base + 2 < N) rp[base + 2] = ex + p1;
    if (base + 3 < N) rp[base + 3] = ex + p2;
    if (t == 255) bsum[blockIdx.x] = woff + sc;
}

__global__ void scan_tops(int* __restrict__ bsum, int B)
{
    int lane = threadIdx.x;  // 64
    int off = 0;
    for (int s = 0; s < B; s += 64) {
        int i = s + lane;
        int v = (i < B) ? bsum[i] : 0;
        int sc = v;
        #pragma unroll
        for (int o = 1; o < 64; o <<= 1) {
            int y = __shfl_up(sc, o);
            if (lane >= o) sc += y;
        }
        if (i < B) bsum[i] = off + sc - v;
        off += __shfl(sc, 63);
    }
}

__global__ void scan_add(int* __restrict__ rp, const int* __restrict__ bsum, int N)
{
    int base = blockIdx.x * 1024 + threadIdx.x * 4;
    int o = bsum[blockIdx.x];
    #pragma unroll
    for (int j = 0; j < 4; ++j)
        if (base + j < N) rp[base + j] += o;
}

__global__ void edge_fill(const int* __restrict__ ei, int E,
                          const int* __restrict__ rp, int* __restrict__ fill,
                          int* __restrict__ col)
{
    int e = blockIdx.x * blockDim.x + threadIdx.x;
    if (e < E) {
        int d = ei[E + e];
        int p = rp[d] + atomicAdd(&fill[d], 1);
        col[p] = ei[e];
    }
}

// ---------------- fused gather + multi-pair GEMM (MFMA, 3-term bf16 split) ----------------
// Per pair p: if rp!=null, A-rows are CSR mean-gathered from src A; else direct rows of A.
// acc[r][c] = sum_p Arow_p[r][:] @ Wmat[w_p][:][c]
// MODE 1: v=(acc+bias0+bias1)*scale+res -> row-LN -> GELU.  MODE 0: store acc.
template<int NP, int MODE, int NTA>
__global__ __launch_bounds__(256, 4)
void gemm_mfma(const float* __restrict__ A0, const int* __restrict__ rp0, const int* __restrict__ dg0, const int* __restrict__ col0, int w0,
               const float* __restrict__ A1, const int* __restrict__ rp1, const int* __restrict__ dg1, const int* __restrict__ col1, int w1,
               const float* __restrict__ A2, const int* __restrict__ rp2, const int* __restrict__ dg2, const int* __restrict__ col2, int w2,
               const unsigned short* __restrict__ phi, const unsigned short* __restrict__ plo,
               const float* __restrict__ bias0, const float* __restrict__ bias1,
               float scale, const float* __restrict__ res,
               const float* __restrict__ g_ln, const float* __restrict__ b_ln,
               float* __restrict__ out, int M)
{
    __shared__ __align__(16) unsigned short As_hi[64 * HD];
    __shared__ __align__(16) unsigned short As_lo[64 * HD];
    __shared__ float psum[4][64];
    __shared__ float psq[4][64];

    const int tid  = threadIdx.x;
    const int w    = tid >> 6;
    const int lane = tid & 63;
    const int c    = lane & 15;
    const int hi4  = lane >> 4;
    const int row0 = blockIdx.x * 64;

    f32x4 acc[4][2];
    #pragma unroll
    for (int rb = 0; rb < 4; ++rb)
        #pragma unroll
        for (int q = 0; q < 2; ++q) acc[rb][q] = (f32x4)0.f;

    #pragma unroll
    for (int p = 0; p < NP; ++p) {
        const float* A = (p == 0) ? A0 : (p == 1) ? A1 : A2;
        const int*  rp = (p == 0) ? rp0 : (p == 1) ? rp1 : rp2;
        const int*  dg = (p == 0) ? dg0 : (p == 1) ? dg1 : dg2;
        const int*  cl = (p == 0) ? col0 : (p == 1) ? col1 : col2;
        const int widx = (p == 0) ? w0 : (p == 1) ? w1 : w2;

        __syncthreads();   // protect LDS reuse from previous pair's reads
        #pragma unroll
        for (int it = 0; it < 4; ++it) {
            int u  = tid + it * 256;
            int r  = u >> 4;
            int k8 = (u & 15) * 8;
            int gr = row0 + r;
            float av[8];
            #pragma unroll
            for (int j = 0; j < 8; ++j) av[j] = 0.f;
            float rs = 1.f;
            if (gr < M) {
                if (rp) {
                    int st = rp[gr];
                    int d  = dg[gr];
                    for (int i = 0; i < d; ++i) {
                        int s = cl[st + i];
                        const f32x4* sp = (const f32x4*)(A + (size_t)s * HD + k8);
                        f32x4 a0 = sp[0], a1 = sp[1];
                        av[0] += a0.x; av[1] += a0.y; av[2] += a0.z; av[3] += a0.w;
                        av[4] += a1.x; av[5] += a1.y; av[6] += a1.z; av[7] += a1.w;
                    }
                    rs = 1.f / (float)(d > 1 ? d : 1);
                } else {
                    const f32x4* ap = (const f32x4*)(A + (size_t)gr * HD + k8);
                    f32x4 a0, a1;
                    if (NTA && p == 0) {
                        a0 = __builtin_nontemporal_load(ap);
                        a1 = __builtin_nontemporal_load(ap + 1);
                    } else {
                        a0 = ap[0]; a1 = ap[1];
                    }
                    av[0] = a0.x; av[1] = a0.y; av[2] = a0.z; av[3] = a0.w;
                    av[4] = a1.x; av[5] = a1.y; av[6] = a1.z; av[7] = a1.w;
                }
            }
            s16x8 vh, vl;
            #pragma unroll
            for (int j = 0; j < 8; ++j) {
                float x = av[j] * rs;
                unsigned short h = bf16_rne(x);
                vh[j] = (short)h;
                vl[j] = (short)bf16_rne(x - bf16_to_f(h));
            }
            int sidx = (r * HD + k8) ^ ((r & 7) << 3);
            *(s16x8*)(As_hi + sidx) = vh;
            *(s16x8*)(As_lo + sidx) = vl;
        }
        __syncthreads();

        #pragma unroll
        for (int ks = 0; ks < 4; ++ks) {
            Frag bh[2], bl[2];
            #pragma unroll
            for (int q = 0; q < 2; ++q) {
                int cbG = w * 2 + q;
                size_t boff = ((((size_t)widx * 8 + cbG) * 4 + ks) * 64 + lane) * 8;
                bh[q].s = *(const s16x8*)(phi + boff);
                bl[q].s = *(const s16x8*)(plo + boff);
            }
            #pragma unroll
            for (int rb = 0; rb < 4; ++rb) {
                int r = rb * 16 + c;
                int sidx = (r * HD + ks * 32 + hi4 * 8) ^ ((r & 7) << 3);
                Frag ah, al;
                ah.s = *(const s16x8*)(As_hi + sidx);
                al.s = *(const s16x8*)(As_lo + sidx);
                #pragma unroll
                for (int q = 0; q < 2; ++q) {
                    acc[rb][q] = __builtin_amdgcn_mfma_f32_16x16x32_bf16(ah.b, bh[q].b, acc[rb][q], 0, 0, 0);
                    acc[rb][q] = __builtin_amdgcn_mfma_f32_16x16x32_bf16(al.b, bh[q].b, acc[rb][q], 0, 0, 0);
                    acc[rb][q] = __builtin_amdgcn_mfma_f32_16x16x32_bf16(ah.b, bl[q].b, acc[rb][q], 0, 0, 0);
                }
            }
        }
    }

    // lane layout: col = (w*2+q)*16 + c ; row = rb*16 + hi4*4 + reg
    if (MODE == 0) {
        #pragma unroll
        for (int rb = 0; rb < 4; ++rb)
            #pragma unroll
            for (int q = 0; q < 2; ++q) {
                int col = (w * 2 + q) * 16 + c;
                #pragma unroll
                for (int reg = 0; reg < 4; ++reg) {
                    int gr = row0 + rb * 16 + hi4 * 4 + reg;
                    if (gr < M) out[(size_t)gr * HD + col] = acc[rb][q][reg];
                }
            }
        return;
    }

    float bsum_[2], gl[2], bb[2];
    #pragma unroll
    for (int q = 0; q < 2; ++q) {
        int col = (w * 2 + q) * 16 + c;
        float b = 0.f;
        if (bias0) b += bias0[col];
        if (bias1) b += bias1[col];
        bsum_[q] = b;
        gl[q] = g_ln[col];
        bb[q] = b_ln[col];
    }

    float v[4][2][4];
    #pragma unroll
    for (int rb = 0; rb < 4; ++rb)
        #pragma unroll
        for (int q = 0; q < 2; ++q) {
            int col = (w * 2 + q) * 16 + c;
            #pragma unroll
            for (int reg = 0; reg < 4; ++reg) {
                int gr = row0 + rb * 16 + hi4 * 4 + reg;
                float r_ = (res && gr < M) ? res[(size_t)gr * HD + col] : 0.f;
                v[rb][q][reg] = (acc[rb][q][reg] + bsum_[q]) * scale + r_;
            }
        }

    #pragma unroll
    for (int rb = 0; rb < 4; ++rb)
        #pragma unroll
        for (int reg = 0; reg < 4; ++reg) {
            float s = v[rb][0][reg] + v[rb][1][reg];
            float qq = v[rb][0][reg] * v[rb][0][reg] + v[rb][1][reg] * v[rb][1][reg];
            #pragma unroll
            for (int m = 1; m <= 8; m <<= 1) {
                s  += __shfl_xor(s, m);
                qq += __shfl_xor(qq, m);
            }
            if (c == 0) {
                int row = rb * 16 + hi4 * 4 + reg;
                psum[w][row] = s;
                psq[w][row]  = qq;
            }
        }
    __syncthreads();

    #pragma unroll
    for (int rb = 0; rb < 4; ++rb)
        #pragma unroll
        for (int reg = 0; reg < 4; ++reg) {
            int row = rb * 16 + hi4 * 4 + reg;
            float S  = psum[0][row] + psum[1][row] + psum[2][row] + psum[3][row];
            float Q  = psq[0][row]  + psq[1][row]  + psq[2][row]  + psq[3][row];
            float mean = S * (1.f / 128.f);
            float var  = Q * (1.f / 128.f) - mean * mean;
            float rstd = rsqrtf(var + 1e-5f);
            int gr = row0 + row;
            if (gr < M) {
                #pragma unroll
                for (int q = 0; q < 2; ++q) {
                    int col = (w * 2 + q) * 16 + c;
                    float t = (v[rb][q][reg] - mean) * rstd * gl[q] + bb[q];
                    out[(size_t)gr * HD + col] = gelu_f(t);
                }
            }
        }
}

// out[e] = dot(P[src[e]], hd[dst[e]])  -- 16 lanes per edge
__global__ void edge_score(const int* __restrict__ ei, int E,
                           const float* __restrict__ P, const float* __restrict__ hdv,
                           float* __restrict__ out)
{
    int t = blockIdx.x * blockDim.x + threadIdx.x;
    int e = t >> 4;
    if (e >= E) return;
    int lane = t & 15;
    int s = ei[e];
    int d = ei[E + e];
    const float4 p0 = *(const float4*)(P + (size_t)s * HD + lane * 8);
    const float4 p1 = *(const float4*)(P + (size_t)s * HD + lane * 8 + 4);
    const float4 h0 = *(const float4*)(hdv + (size_t)d * HD + lane * 8);
    const float4 h1 = *(const float4*)(hdv + (size_t)d * HD + lane * 8 + 4);
    float acc = p0.x * h0.x + p0.y * h0.y + p0.z * h0.z + p0.w * h0.w
              + p1.x * h1.x + p1.y * h1.y + p1.z * h1.z + p1.w * h1.w;
    #pragma unroll
    for (int m = 1; m <= 8; m <<= 1) acc += __shfl_xor(acc, m);
    if (lane == 0) out[e] = acc;
}

extern "C" void kernel_launch(void* const* d_in, const int* in_sizes, int n_in,
                              void* d_out, int out_size, void* d_ws, size_t ws_size,
                              hipStream_t stream)
{
    const float* x_chem    = (const float*)d_in[0];
    const float* x_dis     = (const float*)d_in[1];
    const float* gene_emb  = (const float*)d_in[2];
    const float* proj_W    = (const float*)d_in[3];
    const float* proj_b    = (const float*)d_in[4];
    const float* proj_ln_g = (const float*)d_in[5];
    const float* proj_ln_b = (const float*)d_in[6];
    const float* sage_Wl   = (const float*)d_in[7];
    const float* sage_bl   = (const float*)d_in[8];
    const float* sage_Wr   = (const float*)d_in[9];
    const float* ln_g      = (const float*)d_in[10];
    const float* ln_b      = (const float*)d_in[11];
    const float* W_cd      = (const float*)d_in[12];
    const int*   ei_c2d    = (const int*)d_in[13];
    const int*   ei_d2c    = (const int*)d_in[14];
    const int*   ei_c2g    = (const int*)d_in[15];
    const int*   ei_g2c    = (const int*)d_in[16];
    const int*   pos_edge  = (const int*)d_in[17];
    const int*   neg_edge  = (const int*)d_in[18];
    float* out = (float*)d_out;

    // ---- workspace layout (ping-pong state buffers) ----
    float* ws  = (float*)d_ws;
    float* hc0 = ws;                        // NC*128
    float* hc1 = hc0 + (size_t)T_NC * HD;   // NC*128
    float* hd0 = hc1 + (size_t)T_NC * HD;   // ND*128
    float* hd1 = hd0 + (size_t)T_ND * HD;   // ND*128
    float* hgA = hd1 + (size_t)T_ND * HD;   // NG*128
    float* hgB = hgA + (size_t)T_NG * HD;   // NG*128
    unsigned short* packHi = (unsigned short*)(hgB + (size_t)T_NG * HD);
    unsigned short* packLo = packHi + (size_t)NMAT * HD * HD;
    int* ib = (int*)(packLo + (size_t)NMAT * HD * HD);
    int* deg_dc = ib;               // NC
    int* deg_gc = deg_dc + T_NC;    // NC
    int* deg_cd = deg_gc + T_NC;    // ND
    int* deg_cg = deg_cd + T_ND;    // NG
    int* fil_dc = deg_cg + T_NG;
    int* fil_gc = fil_dc + T_NC;
    int* fil_cd = fil_gc + T_NC;
    int* fil_cg = fil_cd + T_ND;
    int* rp_dc  = fil_cg + T_NG;
    int* rp_gc  = rp_dc + T_NC;
    int* rp_cd  = rp_gc + T_NC;
    int* rp_cg  = rp_cd + T_ND;
    int* col_dc = rp_cg + T_NG;
    int* col_gc = col_dc + T_E;
    int* col_cd = col_gc + T_E;
    int* col_cg = col_cd + T_E;
    int* bsum   = col_cg + T_E;     // 256
    float* P = hc1;                 // free after last layer (final state in hc0)

    const dim3 blk(256);
    const int gC = (T_NC + 63) / 64;
    const int gD = (T_ND + 63) / 64;
    const int gG = (T_NG + 63) / 64;
    const int gE256 = (T_E + 255) / 256;
    const int gEdge = (T_EP * 16 + 255) / 256;
    const int DEGN = 2 * T_NC + T_ND + T_NG;
    const int* NI = nullptr;
    const float* NF = nullptr;

    // ---- one-time: pack weights, build 4 CSRs ----
    pack_weights<<<NMAT, blk, 0, stream>>>(proj_W, sage_Wl, sage_Wr, W_cd, packHi, packLo);
    hipMemsetAsync(deg_dc, 0, (size_t)2 * DEGN * sizeof(int), stream);  // deg + fill

    edge_count<<<gE256, blk, 0, stream>>>(ei_d2c, T_E, deg_dc);
    edge_count<<<gE256, blk, 0, stream>>>(ei_g2c, T_E, deg_gc);
    edge_count<<<gE256, blk, 0, stream>>>(ei_c2d, T_E, deg_cd);
    edge_count<<<gE256, blk, 0, stream>>>(ei_c2g, T_E, deg_cg);

    struct { const int* deg; int* rp; int n; } scans[4] = {
        {deg_dc, rp_dc, T_NC}, {deg_gc, rp_gc, T_NC},
        {deg_cd, rp_cd, T_ND}, {deg_cg, rp_cg, T_NG}};
    for (int i = 0; i < 4; ++i) {
        int B = (scans[i].n + 1023) / 1024;
        scan_local<<<B, blk, 0, stream>>>(scans[i].deg, scans[i].rp, bsum, scans[i].n);
        scan_tops<<<1, 64, 0, stream>>>(bsum, B);
        scan_add<<<B, blk, 0, stream>>>(scans[i].rp, bsum, scans[i].n);
    }

    edge_fill<<<gE256, blk, 0, stream>>>(ei_d2c, T_E, rp_dc, fil_dc, col_dc);
    edge_fill<<<gE256, blk, 0, stream>>>(ei_g2c, T_E, rp_gc, fil_gc, col_gc);
    edge_fill<<<gE256, blk, 0, stream>>>(ei_c2d, T_E, rp_cd, fil_cd, col_cd);
    edge_fill<<<gE256, blk, 0, stream>>>(ei_c2g, T_E, rp_cg, fil_cg, col_cg);

    // ---- projections ----
    gemm_mfma<1, 1, 1><<<gC, blk, 0, stream>>>(
        x_chem, NI, NI, NI, 0,  NF, NI, NI, NI, 0,  NF, NI, NI, NI, 0,
        packHi, packLo, proj_b, nullptr, 1.f, nullptr, proj_ln_g, proj_ln_b, hc0, T_NC);
    gemm_mfma<1, 1, 1><<<gD, blk, 0, stream>>>(
        x_dis, NI, NI, NI, 1,  NF, NI, NI, NI, 0,  NF, NI, NI, NI, 0,
        packHi, packLo, proj_b + HD, nullptr, 1.f, nullptr, proj_ln_g + HD, proj_ln_b + HD, hd0, T_ND);

    for (int l = 0; l < 2; ++l) {
        const float* bl = sage_bl + (size_t)l * 4 * HD;
        const float* lg = ln_g + (size_t)l * 3 * HD;
        const float* lb = ln_b + (size_t)l * 3 * HD;
        const int wl = 2 + l * 4;
        const int wr = 10 + l * 4;
        const int wsum = 19 + l;

        const float* hcC = (l == 0) ? hc0 : hc1;
        float*       hcN = (l == 0) ? hc1 : hc0;
        const float* hdC = (l == 0) ? hd0 : hd1;
        float*       hdN = (l == 0) ? hd1 : hd0;
        const float* hgC = (l == 0) ? gene_emb : hgA;
        float*       hgN = (l == 0) ? hgA : hgB;

        // chem: 0.5*(mean_dc(hd)@Wl1 + bl1 + mean_gc(hg)@Wl3 + bl3 + hc@(Wr1+Wr3)) + hc
        gemm_mfma<3, 1, 0><<<gC, blk, 0, stream>>>(
            hdC, rp_dc, deg_dc, col_dc, wl + 1,
            hgC, rp_gc, deg_gc, col_gc, wl + 3,
            hcC, NI, NI, NI, wsum,
            packHi, packLo, bl + 1 * HD, bl + 3 * HD, 0.5f, hcC, lg + 0 * HD, lb + 0 * HD, hcN, T_NC);
        // dis: mean_cd(hc)@Wl0 + bl0 + hd@Wr0 + hd
        gemm_mfma<2, 1, 0><<<gD, blk, 0, stream>>>(
            hcC, rp_cd, deg_cd, col_cd, wl + 0,
            hdC, NI, NI, NI, wr + 0,
            NF, NI, NI, NI, 0,
            packHi, packLo, bl + 0 * HD, nullptr, 1.f, hdC, lg + 1 * HD, lb + 1 * HD, hdN, T_ND);
        // gene: mean_cg(hc)@Wl2 + bl2 + hg@Wr2 + hg
        gemm_mfma<2, 1, 0><<<gG, blk, 0, stream>>>(
            hcC, rp_cg, deg_cg, col_cg, wl + 2,
            hgC, NI, NI, NI, wr + 2,
            NF, NI, NI, NI, 0,
            packHi, packLo, bl + 2 * HD, nullptr, 1.f, hgC, lg + 2 * HD, lb + 2 * HD, hgN, T_NG);
    }

    // P = hc_final @ W_cd   (hc_final = hc0 after 2 layers)
    gemm_mfma<1, 0, 1><<<gC, blk, 0, stream>>>(
        hc0, NI, NI, NI, 18,  NF, NI, NI, NI, 0,  NF, NI, NI, NI, 0,
        packHi, packLo, nullptr, nullptr, 1.f, nullptr, nullptr, nullptr, P, T_NC);

    edge_score<<<gEdge, blk, 0, stream>>>(pos_edge, T_EP, P, hd0, out);
    edge_score<<<gEdge, blk, 0, stream>>>(neg_edge, T_EP, P, hd0, out + T_EP);
}

// Round 5
// 515.654 us; speedup vs baseline: 7.3424x; 1.1959x over previous
//
#include <hip/hip_runtime.h>

#define HD 128

constexpr int T_NC = 100000;
constexpr int T_ND = 20000;
constexpr int T_NG = 50000;
constexpr int T_E  = 150000;
constexpr int T_EP = 100000;
constexpr int NMAT = 21;          // 2 proj + 8 Wl + 8 Wr + W_cd + 2 summed (Wr1+Wr3 per layer)

typedef __attribute__((ext_vector_type(8))) short   s16x8;
typedef __attribute__((ext_vector_type(8))) __bf16  bf16x8;
typedef __attribute__((ext_vector_type(4))) float   f32x4;

union Frag { s16x8 s; bf16x8 b; };

__device__ __forceinline__ float gelu_f(float x) {
    return 0.5f * x * (1.0f + erff(x * 0.70710678118654752f));
}

__device__ __forceinline__ unsigned short bf16_rne(float x) {
    union { float f; unsigned int u; } c; c.f = x;
    unsigned int u = c.u;
    unsigned int r = (u + 0x7fffu + ((u >> 16) & 1u)) >> 16;
    return (unsigned short)r;
}
__device__ __forceinline__ float bf16_to_f(unsigned short h) {
    union { unsigned int u; float f; } c; c.u = ((unsigned int)h) << 16;
    return c.f;
}

// ---------------- weight packing (once per launch) ----------------
// mats: 0-1 proj, 2-9 sage_Wl[l][e], 10-17 sage_Wr[l][e], 18 W_cd,
//       19-20: sage_Wr[l][1]+sage_Wr[l][3]  (chem right-matrix merged)
__global__ void pack_weights(const float* __restrict__ proj_W,
                             const float* __restrict__ sage_Wl,
                             const float* __restrict__ sage_Wr,
                             const float* __restrict__ W_cd,
                             unsigned short* __restrict__ phi,
                             unsigned short* __restrict__ plo)
{
    int m = blockIdx.x;
    const float* W;
    const float* W2 = nullptr;
    if (m < 2)        W = proj_W  + (size_t)m * HD * HD;
    else if (m < 10)  W = sage_Wl + (size_t)(m - 2) * HD * HD;
    else if (m < 18)  W = sage_Wr + (size_t)(m - 10) * HD * HD;
    else if (m == 18) W = W_cd;
    else {
        int l = m - 19;
        W  = sage_Wr + (size_t)(l * 4 + 1) * HD * HD;
        W2 = sage_Wr + (size_t)(l * 4 + 3) * HD * HD;
    }

    int t = threadIdx.x;          // 256
    int kstep = t >> 6;
    int lane  = t & 63;
    int kbase = kstep * 32 + (lane >> 4) * 8;
    int c     = lane & 15;
    for (int cb = 0; cb < 8; ++cb) {
        int col = cb * 16 + c;
        size_t off = ((((size_t)m * 8 + cb) * 4 + kstep) * 64 + lane) * 8;
        #pragma unroll
        for (int j = 0; j < 8; ++j) {
            float w = W[(size_t)(kbase + j) * HD + col];
            if (W2) w += W2[(size_t)(kbase + j) * HD + col];
            unsigned short h = bf16_rne(w);
            phi[off + j] = h;
            plo[off + j] = bf16_rne(w - bf16_to_f(h));
        }
    }
}

// ---------------- CSR build (once per launch; edge lists are static) ----------------
__global__ void edge_count(const int* __restrict__ ei, int E, int* __restrict__ deg)
{
    int e = blockIdx.x * blockDim.x + threadIdx.x;
    if (e < E) atomicAdd(&deg[ei[E + e]], 1);
}

__global__ void scan_local(const int* __restrict__ deg, int* __restrict__ rp,
                           int* __restrict__ bsum, int N)
{
    __shared__ int wtot[4];
    int t = threadIdx.x;
    int lane = t & 63, w = t >> 6;
    int base = blockIdx.x * 1024 + t * 4;
    int v[4];
    #pragma unroll
    for (int j = 0; j < 4; ++j) v[j] = (base + j < N) ? deg[base + j] : 0;
    int p1 = v[0] + v[1];
    int p2 = p1 + v[2];
    int total = p2 + v[3];
    int sc = total;
    #pragma unroll
    for (int o = 1; o < 64; o <<= 1) {
        int y = __shfl_up(sc, o);
        if (lane >= o) sc += y;
    }
    if (lane == 63) wtot[w] = sc;
    __syncthreads();
    int woff = 0;
    for (int i = 0; i < w; ++i) woff += wtot[i];
    int ex = woff + sc - total;
    if (base + 0 < N) rp[base + 0] = ex;
    if (base + 1 < N) rp[base + 1] = ex + v[0];
    if (base + 2 < N) rp[base + 2] = ex + p1;
    if (base + 3 < N) rp[base + 3] = ex + p2;
    if (t == 255) bsum[blockIdx.x] = woff + sc;
}

__global__ void scan_tops(int* __restrict__ bsum, int B)
{
    int lane = threadIdx.x;  // 64
    int off = 0;
    for (int s = 0; s < B; s += 64) {
        int i = s + lane;
        int v = (i < B) ? bsum[i] : 0;
        int sc = v;
        #pragma unroll
        for (int o = 1; o < 64; o <<= 1) {
            int y = __shfl_up(sc, o);
            if (lane >= o) sc += y;
        }
        if (i < B) bsum[i] = off + sc - v;
        off += __shfl(sc, 63);
    }
}

__global__ void scan_add(int* __restrict__ rp, const int* __restrict__ bsum, int N)
{
    int base = blockIdx.x * 1024 + threadIdx.x * 4;
    int o = bsum[blockIdx.x];
    #pragma unroll
    for (int j = 0; j < 4; ++j)
        if (base + j < N) rp[base + j] += o;
}

__global__ void edge_fill(const int* __restrict__ ei, int E,
                          const int* __restrict__ rp, int* __restrict__ fill,
                          int* __restrict__ col)
{
    int e = blockIdx.x * blockDim.x + threadIdx.x;
    if (e < E) {
        int d = ei[E + e];
        int p = rp[d] + atomicAdd(&fill[d], 1);
        col[p] = ei[e];
    }
}

// ---------------- fused gather + multi-pair GEMM (MFMA, 3-term bf16 split) ----------------
// Up to 3 segments per dispatch (independent outputs), selected by blockIdx range.
// Per pair p (np<=3): if rp!=null, A-rows are CSR mean-gathered from A; else direct rows.
// MODE 1: v=(acc+bias0+bias1)*scale+res -> row-LN -> GELU.  MODE 0: store acc.
// Tile: 32 rows x 128 cols, 4 waves; wave w owns cols [w*32, w*32+32).
struct Seg {
    const float *A0, *A1, *A2;
    const int *rp0, *dg0, *col0;
    const int *rp1, *dg1, *col1;
    const int *rp2, *dg2, *col2;
    const float *bias0, *bias1, *res, *g_ln, *b_ln;
    float* out;
    float scale;
    int w0, w1, w2, np, M, nblk;
};

template<int MODE>
__global__ __launch_bounds__(256, 8)
void fused_gemm(Seg s0, Seg s1, Seg s2,
                const unsigned short* __restrict__ phi,
                const unsigned short* __restrict__ plo)
{
    __shared__ __align__(16) unsigned short As_hi[32 * HD];
    __shared__ __align__(16) unsigned short As_lo[32 * HD];
    __shared__ float psum[4][32];
    __shared__ float psq[4][32];

    int bid = blockIdx.x;
    Seg s;
    if (bid < s0.nblk) s = s0;
    else if (bid < s0.nblk + s1.nblk) { bid -= s0.nblk; s = s1; }
    else { bid -= s0.nblk + s1.nblk; s = s2; }

    const int tid  = threadIdx.x;
    const int w    = tid >> 6;
    const int lane = tid & 63;
    const int c    = lane & 15;
    const int hi4  = lane >> 4;
    const int row0 = bid * 32;

    f32x4 acc[2][2];
    #pragma unroll
    for (int rb = 0; rb < 2; ++rb)
        #pragma unroll
        for (int q = 0; q < 2; ++q) acc[rb][q] = (f32x4)0.f;

    for (int p = 0; p < s.np; ++p) {
        const float* A = (p == 0) ? s.A0 : (p == 1) ? s.A1 : s.A2;
        const int*  rp = (p == 0) ? s.rp0 : (p == 1) ? s.rp1 : s.rp2;
        const int*  dg = (p == 0) ? s.dg0 : (p == 1) ? s.dg1 : s.dg2;
        const int*  cl = (p == 0) ? s.col0 : (p == 1) ? s.col1 : s.col2;
        const int widx = (p == 0) ? s.w0 : (p == 1) ? s.w1 : s.w2;

        __syncthreads();   // protect LDS reuse from previous pair's reads
        for (int it = 0; it < 2; ++it) {
            int u  = tid + it * 256;
            int r  = u >> 4;
            int k8 = (u & 15) * 8;
            int gr = row0 + r;
            float av[8];
            #pragma unroll
            for (int j = 0; j < 8; ++j) av[j] = 0.f;
            float rs = 1.f;
            if (gr < s.M) {
                if (rp) {
                    int st = rp[gr];
                    int d  = dg[gr];
                    int i = 0;
                    for (; i + 2 <= d; i += 2) {        // 2-deep pipelined gather
                        int e0 = cl[st + i];
                        int e1 = cl[st + i + 1];
                        const f32x4* q0 = (const f32x4*)(A + (size_t)e0 * HD + k8);
                        const f32x4* q1 = (const f32x4*)(A + (size_t)e1 * HD + k8);
                        f32x4 a0 = q0[0], a1 = q0[1], b0 = q1[0], b1 = q1[1];
                        av[0] += a0.x + b0.x; av[1] += a0.y + b0.y;
                        av[2] += a0.z + b0.z; av[3] += a0.w + b0.w;
                        av[4] += a1.x + b1.x; av[5] += a1.y + b1.y;
                        av[6] += a1.z + b1.z; av[7] += a1.w + b1.w;
                    }
                    if (i < d) {
                        int e0 = cl[st + i];
                        const f32x4* q0 = (const f32x4*)(A + (size_t)e0 * HD + k8);
                        f32x4 a0 = q0[0], a1 = q0[1];
                        av[0] += a0.x; av[1] += a0.y; av[2] += a0.z; av[3] += a0.w;
                        av[4] += a1.x; av[5] += a1.y; av[6] += a1.z; av[7] += a1.w;
                    }
                    rs = 1.f / (float)(d > 1 ? d : 1);
                } else {
                    const f32x4* ap = (const f32x4*)(A + (size_t)gr * HD + k8);
                    f32x4 a0 = ap[0], a1 = ap[1];
                    av[0] = a0.x; av[1] = a0.y; av[2] = a0.z; av[3] = a0.w;
                    av[4] = a1.x; av[5] = a1.y; av[6] = a1.z; av[7] = a1.w;
                }
            }
            s16x8 vh, vl;
            #pragma unroll
            for (int j = 0; j < 8; ++j) {
                float x = av[j] * rs;
                unsigned short h = bf16_rne(x);
                vh[j] = (short)h;
                vl[j] = (short)bf16_rne(x - bf16_to_f(h));
            }
            int sidx = (r * HD + k8) ^ ((r & 7) << 3);
            *(s16x8*)(As_hi + sidx) = vh;
            *(s16x8*)(As_lo + sidx) = vl;
        }
        __syncthreads();

        #pragma unroll
        for (int ks = 0; ks < 4; ++ks) {
            Frag bh[2], bl[2];
            #pragma unroll
            for (int q = 0; q < 2; ++q) {
                int cbG = w * 2 + q;
                size_t boff = ((((size_t)widx * 8 + cbG) * 4 + ks) * 64 + lane) * 8;
                bh[q].s = *(const s16x8*)(phi + boff);
                bl[q].s = *(const s16x8*)(plo + boff);
            }
            #pragma unroll
            for (int rb = 0; rb < 2; ++rb) {
                int r = rb * 16 + c;
                int sidx = (r * HD + ks * 32 + hi4 * 8) ^ ((r & 7) << 3);
                Frag ah, al;
                ah.s = *(const s16x8*)(As_hi + sidx);
                al.s = *(const s16x8*)(As_lo + sidx);
                #pragma unroll
                for (int q = 0; q < 2; ++q) {
                    acc[rb][q] = __builtin_amdgcn_mfma_f32_16x16x32_bf16(ah.b, bh[q].b, acc[rb][q], 0, 0, 0);
                    acc[rb][q] = __builtin_amdgcn_mfma_f32_16x16x32_bf16(al.b, bh[q].b, acc[rb][q], 0, 0, 0);
                    acc[rb][q] = __builtin_amdgcn_mfma_f32_16x16x32_bf16(ah.b, bl[q].b, acc[rb][q], 0, 0, 0);
                }
            }
        }
    }

    // lane layout: col = (w*2+q)*16 + c ; row = rb*16 + hi4*4 + reg
    if (MODE == 0) {
        #pragma unroll
        for (int rb = 0; rb < 2; ++rb)
            #pragma unroll
            for (int q = 0; q < 2; ++q) {
                int col = (w * 2 + q) * 16 + c;
                #pragma unroll
                for (int reg = 0; reg < 4; ++reg) {
                    int gr = row0 + rb * 16 + hi4 * 4 + reg;
                    if (gr < s.M) s.out[(size_t)gr * HD + col] = acc[rb][q][reg];
                }
            }
        return;
    }

    float bsum_[2], gl[2], bb[2];
    #pragma unroll
    for (int q = 0; q < 2; ++q) {
        int col = (w * 2 + q) * 16 + c;
        float b = 0.f;
        if (s.bias0) b += s.bias0[col];
        if (s.bias1) b += s.bias1[col];
        bsum_[q] = b;
        gl[q] = s.g_ln[col];
        bb[q] = s.b_ln[col];
    }

    float v[2][2][4];
    #pragma unroll
    for (int rb = 0; rb < 2; ++rb)
        #pragma unroll
        for (int q = 0; q < 2; ++q) {
            int col = (w * 2 + q) * 16 + c;
            #pragma unroll
            for (int reg = 0; reg < 4; ++reg) {
                int gr = row0 + rb * 16 + hi4 * 4 + reg;
                float r_ = (s.res && gr < s.M) ? s.res[(size_t)gr * HD + col] : 0.f;
                v[rb][q][reg] = (acc[rb][q][reg] + bsum_[q]) * s.scale + r_;
            }
        }

    #pragma unroll
    for (int rb = 0; rb < 2; ++rb)
        #pragma unroll
        for (int reg = 0; reg < 4; ++reg) {
            float sm = v[rb][0][reg] + v[rb][1][reg];
            float qq = v[rb][0][reg] * v[rb][0][reg] + v[rb][1][reg] * v[rb][1][reg];
            #pragma unroll
            for (int m = 1; m <= 8; m <<= 1) {
                sm += __shfl_xor(sm, m);
                qq += __shfl_xor(qq, m);
            }
            if (c == 0) {
                int row = rb * 16 + hi4 * 4 + reg;
                psum[w][row] = sm;
                psq[w][row]  = qq;
            }
        }
    __syncthreads();

    #pragma unroll
    for (int rb = 0; rb < 2; ++rb)
        #pragma unroll
        for (int reg = 0; reg < 4; ++reg) {
            int row = rb * 16 + hi4 * 4 + reg;
            float S  = psum[0][row] + psum[1][row] + psum[2][row] + psum[3][row];
            float Q  = psq[0][row]  + psq[1][row]  + psq[2][row]  + psq[3][row];
            float mean = S * (1.f / 128.f);
            float var  = Q * (1.f / 128.f) - mean * mean;
            float rstd = rsqrtf(var + 1e-5f);
            int gr = row0 + row;
            if (gr < s.M) {
                #pragma unroll
                for (int q = 0; q < 2; ++q) {
                    int col = (w * 2 + q) * 16 + c;
                    float t = (v[rb][q][reg] - mean) * rstd * gl[q] + bb[q];
                    s.out[(size_t)gr * HD + col] = gelu_f(t);
                }
            }
        }
}

// out[e] = dot(P[src[e]], hd[dst[e]])  -- 16 lanes per edge
__global__ void edge_score(const int* __restrict__ ei, int E,
                           const float* __restrict__ P, const float* __restrict__ hdv,
                           float* __restrict__ out)
{
    int t = blockIdx.x * blockDim.x + threadIdx.x;
    int e = t >> 4;
    if (e >= E) return;
    int lane = t & 15;
    int s = ei[e];
    int d = ei[E + e];
    const float4 p0 = *(const float4*)(P + (size_t)s * HD + lane * 8);
    const float4 p1 = *(const float4*)(P + (size_t)s * HD + lane * 8 + 4);
    const float4 h0 = *(const float4*)(hdv + (size_t)d * HD + lane * 8);
    const float4 h1 = *(const float4*)(hdv + (size_t)d * HD + lane * 8 + 4);
    float acc = p0.x * h0.x + p0.y * h0.y + p0.z * h0.z + p0.w * h0.w
              + p1.x * h1.x + p1.y * h1.y + p1.z * h1.z + p1.w * h1.w;
    #pragma unroll
    for (int m = 1; m <= 8; m <<= 1) acc += __shfl_xor(acc, m);
    if (lane == 0) out[e] = acc;
}

extern "C" void kernel_launch(void* const* d_in, const int* in_sizes, int n_in,
                              void* d_out, int out_size, void* d_ws, size_t ws_size,
                              hipStream_t stream)
{
    const float* x_chem    = (const float*)d_in[0];
    const float* x_dis     = (const float*)d_in[1];
    const float* gene_emb  = (const float*)d_in[2];
    const float* proj_W    = (const float*)d_in[3];
    const float* proj_b    = (const float*)d_in[4];
    const float* proj_ln_g = (const float*)d_in[5];
    const float* proj_ln_b = (const float*)d_in[6];
    const float* sage_Wl   = (const float*)d_in[7];
    const float* sage_bl   = (const float*)d_in[8];
    const float* sage_Wr   = (const float*)d_in[9];
    const float* ln_g      = (const float*)d_in[10];
    const float* ln_b      = (const float*)d_in[11];
    const float* W_cd      = (const float*)d_in[12];
    const int*   ei_c2d    = (const int*)d_in[13];
    const int*   ei_d2c    = (const int*)d_in[14];
    const int*   ei_c2g    = (const int*)d_in[15];
    const int*   ei_g2c    = (const int*)d_in[16];
    const int*   pos_edge  = (const int*)d_in[17];
    const int*   neg_edge  = (const int*)d_in[18];
    float* out = (float*)d_out;

    // ---- workspace layout (ping-pong state buffers) ----
    float* ws  = (float*)d_ws;
    float* hc0 = ws;                        // NC*128
    float* hc1 = hc0 + (size_t)T_NC * HD;   // NC*128
    float* hd0 = hc1 + (size_t)T_NC * HD;   // ND*128
    float* hd1 = hd0 + (size_t)T_ND * HD;   // ND*128
    float* hgA = hd1 + (size_t)T_ND * HD;   // NG*128
    float* hgB = hgA + (size_t)T_NG * HD;   // NG*128
    unsigned short* packHi = (unsigned short*)(hgB + (size_t)T_NG * HD);
    unsigned short* packLo = packHi + (size_t)NMAT * HD * HD;
    int* ib = (int*)(packLo + (size_t)NMAT * HD * HD);
    int* deg_dc = ib;               // NC
    int* deg_gc = deg_dc + T_NC;    // NC
    int* deg_cd = deg_gc + T_NC;    // ND
    int* deg_cg = deg_cd + T_ND;    // NG
    int* fil_dc = deg_cg + T_NG;
    int* fil_gc = fil_dc + T_NC;
    int* fil_cd = fil_gc + T_NC;
    int* fil_cg = fil_cd + T_ND;
    int* rp_dc  = fil_cg + T_NG;
    int* rp_gc  = rp_dc + T_NC;
    int* rp_cd  = rp_gc + T_NC;
    int* rp_cg  = rp_cd + T_ND;
    int* col_dc = rp_cg + T_NG;
    int* col_gc = col_dc + T_E;
    int* col_cd = col_gc + T_E;
    int* col_cg = col_cd + T_E;
    int* bsum   = col_cg + T_E;     // 256
    float* P = hc1;                 // free after last layer (final state in hc0)

    const dim3 blk(256);
    const int gC = (T_NC + 31) / 32;   // 3125
    const int gD = (T_ND + 31) / 32;   // 625
    const int gG = (T_NG + 31) / 32;   // 1563
    const int gE256 = (T_E + 255) / 256;
    const int gEdge = (T_EP * 16 + 255) / 256;
    const int DEGN = 2 * T_NC + T_ND + T_NG;

    // ---- one-time: pack weights, build 4 CSRs ----
    pack_weights<<<NMAT, blk, 0, stream>>>(proj_W, sage_Wl, sage_Wr, W_cd, packHi, packLo);
    hipMemsetAsync(deg_dc, 0, (size_t)2 * DEGN * sizeof(int), stream);  // deg + fill

    edge_count<<<gE256, blk, 0, stream>>>(ei_d2c, T_E, deg_dc);
    edge_count<<<gE256, blk, 0, stream>>>(ei_g2c, T_E, deg_gc);
    edge_count<<<gE256, blk, 0, stream>>>(ei_c2d, T_E, deg_cd);
    edge_count<<<gE256, blk, 0, stream>>>(ei_c2g, T_E, deg_cg);

    struct { const int* deg; int* rp; int n; } scans[4] = {
        {deg_dc, rp_dc, T_NC}, {deg_gc, rp_gc, T_NC},
        {deg_cd, rp_cd, T_ND}, {deg_cg, rp_cg, T_NG}};
    for (int i = 0; i < 4; ++i) {
        int B = (scans[i].n + 1023) / 1024;
        scan_local<<<B, blk, 0, stream>>>(scans[i].deg, scans[i].rp, bsum, scans[i].n);
        scan_tops<<<1, 64, 0, stream>>>(bsum, B);
        scan_add<<<B, blk, 0, stream>>>(scans[i].rp, bsum, scans[i].n);
    }

    edge_fill<<<gE256, blk, 0, stream>>>(ei_d2c, T_E, rp_dc, fil_dc, col_dc);
    edge_fill<<<gE256, blk, 0, stream>>>(ei_g2c, T_E, rp_gc, fil_gc, col_gc);
    edge_fill<<<gE256, blk, 0, stream>>>(ei_c2d, T_E, rp_cd, fil_cd, col_cd);
    edge_fill<<<gE256, blk, 0, stream>>>(ei_c2g, T_E, rp_cg, fil_cg, col_cg);

    Seg z{};  // empty segment (nblk = 0)

    // ---- projections (merged into one dispatch) ----
    {
        Seg pc{};
        pc.A0 = x_chem; pc.w0 = 0; pc.np = 1;
        pc.bias0 = proj_b; pc.g_ln = proj_ln_g; pc.b_ln = proj_ln_b;
        pc.scale = 1.f; pc.out = hc0; pc.M = T_NC; pc.nblk = gC;
        Seg pd{};
        pd.A0 = x_dis; pd.w0 = 1; pd.np = 1;
        pd.bias0 = proj_b + HD; pd.g_ln = proj_ln_g + HD; pd.b_ln = proj_ln_b + HD;
        pd.scale = 1.f; pd.out = hd0; pd.M = T_ND; pd.nblk = gD;
        fused_gemm<1><<<gC + gD, blk, 0, stream>>>(pc, pd, z, packHi, packLo);
    }

    for (int l = 0; l < 2; ++l) {
        const float* bl = sage_bl + (size_t)l * 4 * HD;
        const float* lg = ln_g + (size_t)l * 3 * HD;
        const float* lb = ln_b + (size_t)l * 3 * HD;
        const int wl = 2 + l * 4;
        const int wr = 10 + l * 4;
        const int wsum = 19 + l;

        const float* hcC = (l == 0) ? hc0 : hc1;
        float*       hcN = (l == 0) ? hc1 : hc0;
        const float* hdC = (l == 0) ? hd0 : hd1;
        float*       hdN = (l == 0) ? hd1 : hd0;
        const float* hgC = (l == 0) ? gene_emb : hgA;
        float*       hgN = (l == 0) ? hgA : hgB;

        // chem: 0.5*(mean_dc(hd)@Wl1 + bl1 + mean_gc(hg)@Wl3 + bl3 + hc@(Wr1+Wr3)) + hc
        Seg sc{};
        sc.A0 = hdC; sc.rp0 = rp_dc; sc.dg0 = deg_dc; sc.col0 = col_dc; sc.w0 = wl + 1;
        sc.A1 = hgC; sc.rp1 = rp_gc; sc.dg1 = deg_gc; sc.col1 = col_gc; sc.w1 = wl + 3;
        sc.A2 = hcC; sc.w2 = wsum;
        sc.np = 3; sc.bias0 = bl + 1 * HD; sc.bias1 = bl + 3 * HD;
        sc.scale = 0.5f; sc.res = hcC; sc.g_ln = lg; sc.b_ln = lb;
        sc.out = hcN; sc.M = T_NC; sc.nblk = gC;
        // dis: mean_cd(hc)@Wl0 + bl0 + hd@Wr0 + hd
        Seg sd{};
        sd.A0 = hcC; sd.rp0 = rp_cd; sd.dg0 = deg_cd; sd.col0 = col_cd; sd.w0 = wl + 0;
        sd.A1 = hdC; sd.w1 = wr + 0;
        sd.np = 2; sd.bias0 = bl + 0 * HD;
        sd.scale = 1.f; sd.res = hdC; sd.g_ln = lg + HD; sd.b_ln = lb + HD;
        sd.out = hdN; sd.M = T_ND; sd.nblk = gD;
        // gene: mean_cg(hc)@Wl2 + bl2 + hg@Wr2 + hg
        Seg sg{};
        sg.A0 = hcC; sg.rp0 = rp_cg; sg.dg0 = deg_cg; sg.col0 = col_cg; sg.w0 = wl + 2;
        sg.A1 = hgC; sg.w1 = wr + 2;
        sg.np = 2; sg.bias0 = bl + 2 * HD;
        sg.scale = 1.f; sg.res = hgC; sg.g_ln = lg + 2 * HD; sg.b_ln = lb + 2 * HD;
        sg.out = hgN; sg.M = T_NG; sg.nblk = gG;

        fused_gemm<1><<<gC + gD + gG, blk, 0, stream>>>(sc, sd, sg, packHi, packLo);
    }

    // P = hc_final @ W_cd   (hc_final = hc0 after 2 layers)
    {
        Seg sp{};
        sp.A0 = hc0; sp.w0 = 18; sp.np = 1;
        sp.scale = 1.f; sp.out = P; sp.M = T_NC; sp.nblk = gC;
        fused_gemm<0><<<gC, blk, 0, stream>>>(sp, z, z, packHi, packLo);
    }

    edge_score<<<gEdge, blk, 0, stream>>>(pos_edge, T_EP, P, hd0, out);
    edge_score<<<gEdge, blk, 0, stream>>>(neg_edge, T_EP, P, hd0, out + T_EP);
}